// Round 8
// baseline (627.355 us; speedup 1.0000x reference)
//
#include <hip/hip_runtime.h>

#define NUSER 20000
#define NITEM 40000
#define NNODE 60000
#define DIM   64
#define NE    1000000   // per direction; total directed edges = 2*NE
#define KUSER 40
#define KITEM 10

typedef __attribute__((ext_vector_type(8))) short short8v;
typedef __attribute__((ext_vector_type(4))) float floatx4;

__device__ inline short bf16rne(float f) {
    unsigned u = __builtin_bit_cast(unsigned, f);
    unsigned r = (u + 0x7fffu + ((u >> 16) & 1u)) >> 16;
    return (short)r;
}
__device__ inline unsigned cvt_pk_bf16(float lo, float hi) {   // dst.lo16=bf16(lo), dst.hi16=bf16(hi)
    unsigned r;
    asm("v_cvt_pk_bf16_f32 %0, %1, %2" : "=v"(r) : "v"(lo), "v"(hi));
    return r;
}
__device__ inline float bflo(unsigned v) { return __builtin_bit_cast(float, v << 16); }
__device__ inline float bfhi(unsigned v) { return __builtin_bit_cast(float, v & 0xffff0000u); }

// ---------------- degree / norm ----------------
__global__ __launch_bounds__(256) void k_count(const int* __restrict__ dst, int* __restrict__ cnt, int n) {
    int i = blockIdx.x * 256 + threadIdx.x;
    if (i < n) atomicAdd(&cnt[dst[i]], 1);
}

__global__ __launch_bounds__(256) void k_dinv(const int* __restrict__ cnt, float* __restrict__ dinv) {
    int i = blockIdx.x * 256 + threadIdx.x;
    if (i < NNODE) dinv[i] = 1.0f / sqrtf((float)(cnt[i] + 1));  // +1 self loop
}

// ---------------- exclusive scan (3-kernel) ----------------
__global__ __launch_bounds__(256) void k_scanA(const int* __restrict__ v, int* __restrict__ excl,
                                               int* __restrict__ bsum, int n) {
    __shared__ int s[256];
    int t = threadIdx.x, i = blockIdx.x * 256 + t;
    int orig = (i < n) ? v[i] : 0;
    s[t] = orig; __syncthreads();
    #pragma unroll
    for (int off = 1; off < 256; off <<= 1) {
        int u = (t >= off) ? s[t - off] : 0;
        __syncthreads();
        s[t] += u;
        __syncthreads();
    }
    if (i < n) excl[i] = s[t] - orig;
    if (t == 255) bsum[blockIdx.x] = s[255];
}

__global__ __launch_bounds__(256) void k_scanB(int* __restrict__ bsum, int nb) {
    __shared__ int s[256];
    int t = threadIdx.x;
    int orig = (t < nb) ? bsum[t] : 0;
    s[t] = orig; __syncthreads();
    #pragma unroll
    for (int off = 1; off < 256; off <<= 1) {
        int u = (t >= off) ? s[t - off] : 0;
        __syncthreads();
        s[t] += u;
        __syncthreads();
    }
    if (t < nb) bsum[t] = s[t] - orig;  // exclusive
}

__global__ __launch_bounds__(256) void k_scanC(int* __restrict__ excl, const int* __restrict__ bsum,
                                               int* __restrict__ cursor, int n) {
    int i = blockIdx.x * 256 + threadIdx.x;
    if (i < n) {
        int v = excl[i] + bsum[blockIdx.x];
        excl[i] = v;
        cursor[i] = v;
    }
    if (i == 0) excl[n] = 2 * NE;
}

// fill packed CSR: entry = (bf16bits(dinv[src]) << 16) | src   (src < 65536)
__global__ __launch_bounds__(256) void k_fill(const int* __restrict__ src, const int* __restrict__ dst,
                                              const float* __restrict__ dinv, int* __restrict__ cursor,
                                              unsigned* __restrict__ csr_pkd, int n) {
    int i = blockIdx.x * 256 + threadIdx.x;
    if (i >= n) return;
    int s = src[i], d = dst[i];
    unsigned pk = ((unsigned)(unsigned short)bf16rne(dinv[s]) << 16) | (unsigned)s;
    int pos = atomicAdd(&cursor[d], 1);
    csr_pkd[pos] = pk;
}

// ---------------- weight transpose + bf16 cast, k-blocked: Btb[k/32][n][k%32] ----------------
__global__ __launch_bounds__(256) void k_transpose_bf16(const float* __restrict__ B, short* __restrict__ Btb,
                                                        int K, int N) {
    __shared__ float s[16][17];
    int t = threadIdx.x, tx = t & 15, ty = t >> 4;
    int k0 = blockIdx.x * 16, n0 = blockIdx.y * 16;
    s[ty][tx] = B[(size_t)(k0 + ty) * N + n0 + tx];
    __syncthreads();
    int k = k0 + tx, n = n0 + ty;
    Btb[(size_t)(k >> 5) * (N * 32) + n * 32 + (k & 31)] = bf16rne(s[tx][ty]);
}

// ---------------- prep: Bcat (256x128 block-diag {Wv,Wt,Wv2,Wt2}, k-blocked bf16), bw=b@W, bb=2b ----------------
__global__ __launch_bounds__(256) void k_prep(const float* __restrict__ Wv, const float* __restrict__ Wt,
                                              const float* __restrict__ bv, const float* __restrict__ bt,
                                              short* __restrict__ Bcat, float* __restrict__ bw, float* __restrict__ bb) {
    __shared__ float Wld[2][64][65];
    __shared__ float W2ld[2][64][65];
    int t = threadIdx.x;
    for (int id = t; id < 8192; id += 256) {
        int z = id >> 12, k = (id >> 6) & 63, n = id & 63;
        Wld[z][k][n] = (z ? Wt : Wv)[k * 64 + n];
    }
    __syncthreads();
    for (int id = t; id < 8192; id += 256) {
        int z = id >> 12, k = (id >> 6) & 63, n = id & 63;
        float a = 0.f;
        #pragma unroll 8
        for (int m = 0; m < 64; m++) a += Wld[z][k][m] * Wld[z][m][n];
        W2ld[z][k][n] = a;
    }
    __syncthreads();
    for (int id = t; id < 32768; id += 256) {
        int k = id >> 7, n = id & 127;
        int kb = k >> 6, kk = k & 63;
        float v = 0.f;
        if (kb == 0)      { if (n < 64)  v = Wld[0][kk][n]; }
        else if (kb == 1) { if (n >= 64) v = Wld[1][kk][n - 64]; }
        else if (kb == 2) { if (n < 64)  v = W2ld[0][kk][n]; }
        else              { if (n >= 64) v = W2ld[1][kk][n - 64]; }
        Bcat[(k >> 5) * 4096 + n * 32 + (k & 31)] = bf16rne(v);
    }
    if (t < 128) {
        int z = t >> 6, n = t & 63;
        const float* b = z ? bt : bv;
        float a = 0.f;
        #pragma unroll 8
        for (int k = 0; k < 64; k++) a += b[k] * Wld[z][k][n];
        bw[t] = a;
        bb[t] = 2.f * b[n];
    }
}

// ---------------- fused MLP: X = l2n(lrelu(A@W1+b1)@W2+b2), MFMA both GEMMs ----------------
#define AP   40
#define MIDP 264
__global__ __launch_bounds__(256) void mlp_fused(const float* __restrict__ A, const short* __restrict__ B1t,
                                                 const float* __restrict__ b1, const short* __restrict__ B2t,
                                                 const float* __restrict__ b2, float* __restrict__ X,
                                                 unsigned* __restrict__ xbf, int boff, int K) {
    __shared__ short smem[2 * 64 * AP + 2 * 256 * AP];
    short* As = smem;                 // [2][64*AP]
    short* Bs = smem + 2 * 64 * AP;   // [2][256*AP]; reused as mid[64][MIDP]
    const int tid = threadIdx.x;
    const int lane = tid & 63, wid = tid >> 6;
    const int rowBase = blockIdx.x * 64;

    const int sar = tid >> 2, sac = (tid & 3) * 8;
    const float* aptr = A + (size_t)(rowBase + sar) * K + sac;

    const int fk = (lane >> 4) * 8;
    const int faoff = (lane & 15) * AP + fk;
    const int fboff = (wid * 64 + (lane & 15)) * AP + fk;

    floatx4 acc[4][4];
    #pragma unroll
    for (int m = 0; m < 4; m++)
        #pragma unroll
        for (int n = 0; n < 4; n++) acc[m][n] = (floatx4)0.f;

    float4 ra0, ra1;
    short8v rb[4];
    const int nk = K >> 5;

    auto ldg = [&](int ks) {
        const float* ap = aptr + ks * 32;
        ra0 = *(const float4*)(ap);
        ra1 = *(const float4*)(ap + 4);
        const short* bsrc = B1t + (size_t)ks * 8192 + tid * 8;
        #pragma unroll
        for (int it = 0; it < 4; it++) rb[it] = *(const short8v*)(bsrc + it * 2048);
    };
    auto stv = [&](int buf) {
        uint4 av;
        av.x = cvt_pk_bf16(ra0.x, ra0.y); av.y = cvt_pk_bf16(ra0.z, ra0.w);
        av.z = cvt_pk_bf16(ra1.x, ra1.y); av.w = cvt_pk_bf16(ra1.z, ra1.w);
        *(uint4*)&As[buf * (64 * AP) + sar * AP + sac] = av;
        #pragma unroll
        for (int it = 0; it < 4; it++)
            *(short8v*)&Bs[buf * (256 * AP) + (sar + it * 64) * AP + sac] = rb[it];
    };

    ldg(0); stv(0);
    __syncthreads();
    int cur = 0;
    for (int ks = 0; ks < nk; ++ks) {
        if (ks + 1 < nk) ldg(ks + 1);
        short8v a[4], b[4];
        #pragma unroll
        for (int m = 0; m < 4; m++) a[m] = *(const short8v*)&As[cur * (64 * AP) + faoff + m * 16 * AP];
        #pragma unroll
        for (int n = 0; n < 4; n++) b[n] = *(const short8v*)&Bs[cur * (256 * AP) + fboff + n * 16 * AP];
        #pragma unroll
        for (int m = 0; m < 4; m++)
            #pragma unroll
            for (int n = 0; n < 4; n++)
                acc[m][n] = __builtin_amdgcn_mfma_f32_16x16x32_bf16(a[m], b[n], acc[m][n], 0, 0, 0);
        if (ks + 1 < nk) stv(cur ^ 1);
        __syncthreads();
        cur ^= 1;
    }

    // phase 2: bias + lrelu -> bf16 mid in LDS
    short* mid = Bs;
    float bcol[4];
    #pragma unroll
    for (int n = 0; n < 4; n++) bcol[n] = b1[wid * 64 + n * 16 + (lane & 15)];
    #pragma unroll
    for (int m = 0; m < 4; m++)
        #pragma unroll
        for (int n = 0; n < 4; n++)
            #pragma unroll
            for (int q = 0; q < 4; q++) {
                int row = m * 16 + (lane >> 4) * 4 + q;
                int col = wid * 64 + n * 16 + (lane & 15);
                float v = acc[m][n][q] + bcol[n];
                v = v > 0.f ? v : 0.01f * v;
                mid[row * MIDP + col] = bf16rne(v);
            }
    __syncthreads();

    // phase 3: temp = mid @ W2
    floatx4 acc2[4];
    #pragma unroll
    for (int n2 = 0; n2 < 4; n2++) acc2[n2] = (floatx4)0.f;
    const int arow = wid * 16 + (lane & 15);
    #pragma unroll
    for (int ks2 = 0; ks2 < 8; ++ks2) {
        short8v af = *(const short8v*)&mid[arow * MIDP + ks2 * 32 + fk];
        const short* bp = B2t + ks2 * 2048 + fk;
        short8v bf4[4];
        #pragma unroll
        for (int n2 = 0; n2 < 4; n2++) bf4[n2] = *(const short8v*)(bp + (n2 * 16 + (lane & 15)) * 32);
        #pragma unroll
        for (int n2 = 0; n2 < 4; n2++)
            acc2[n2] = __builtin_amdgcn_mfma_f32_16x16x32_bf16(af, bf4[n2], acc2[n2], 0, 0, 0);
    }

    // phase 4: bias + row-L2-norm, write X (f32) + xbf (packed bf16 pairs)
    float b2c[4];
    #pragma unroll
    for (int n2 = 0; n2 < 4; n2++) b2c[n2] = b2[n2 * 16 + (lane & 15)];
    #pragma unroll
    for (int q = 0; q < 4; ++q) {
        float v[4]; float ss = 0.f;
        #pragma unroll
        for (int n2 = 0; n2 < 4; n2++) { v[n2] = acc2[n2][q] + b2c[n2]; ss += v[n2] * v[n2]; }
        ss += __shfl_xor(ss, 1, 64);
        ss += __shfl_xor(ss, 2, 64);
        ss += __shfl_xor(ss, 4, 64);
        ss += __shfl_xor(ss, 8, 64);
        float sc = 1.f / fmaxf(sqrtf(ss), 1e-12f);
        int grow = rowBase + wid * 16 + (lane >> 4) * 4 + q;
        #pragma unroll
        for (int n2 = 0; n2 < 4; n2++) {
            float xn = v[n2] * sc;
            X[(size_t)grow * 64 + n2 * 16 + (lane & 15)] = xn;
            float pn = __shfl_xor(xn, 1, 64);
            if (!(lane & 1))
                xbf[(size_t)grow * 64 + boff + n2 * 8 + ((lane & 15) >> 1)] = cvt_pk_bf16(xn, pn);
        }
    }
}

// ---------------- pref rows: copy + L2-normalize, write f32 + packed bf16 ----------------
__global__ __launch_bounds__(256) void k_l2n_pref(const float* __restrict__ prefv, const float* __restrict__ preft,
                                                  float* __restrict__ xv, float* __restrict__ xt,
                                                  unsigned* __restrict__ xbf) {
    int row = blockIdx.x * 4 + (threadIdx.x >> 6);
    int lane = threadIdx.x & 63;
    if (row >= NUSER) return;
    const float* p = blockIdx.y ? preft : prefv;
    float* x = blockIdx.y ? xt : xv;
    float v = p[(size_t)row * 64 + lane];
    float ss = v * v;
    #pragma unroll
    for (int off = 32; off >= 1; off >>= 1) ss += __shfl_xor(ss, off, 64);
    float xn = v / fmaxf(sqrtf(ss), 1e-12f);
    x[(size_t)row * 64 + lane] = xn;
    float pn = __shfl_xor(xn, 1, 64);
    if (!(lane & 1))
        xbf[(size_t)row * 64 + (blockIdx.y ? 32 : 0) + (lane >> 1)] = cvt_pk_bf16(xn, pn);
}

// ---------------- packed gather: out = A_hat(in) (bf16 in/out); optional s = A_hat(1) ----------------
template<bool WITH_S>
__global__ __launch_bounds__(256) void k_gather_p(const int* __restrict__ rowptr, const unsigned* __restrict__ csr_pkd,
                                                  const float* __restrict__ dinv, const unsigned* __restrict__ in_bf,
                                                  unsigned* __restrict__ out_bf, float* __restrict__ s_out) {
    int row = blockIdx.x * 4 + (threadIdx.x >> 6);
    int lane = threadIdx.x & 63;
    if (row >= NNODE) return;
    int p0 = rowptr[row], p1 = rowptr[row + 1];
    float dr = dinv[row];
    unsigned sv = in_bf[(size_t)row * 64 + lane];
    float ax0 = dr * bflo(sv), ay0 = dr * bfhi(sv);
    float ax1 = 0.f, ay1 = 0.f;
    float wsum = 0.f;
    for (int p = p0; p < p1; p += 64) {
        int c = p1 - p; if (c > 64) c = 64;
        unsigned pk = (lane < c) ? csr_pkd[p + lane] : 0u;
        if (WITH_S) wsum += bfhi(pk);
        int j = 0;
        for (; j + 4 <= c; j += 4) {
            unsigned e0 = __shfl(pk, j, 64),     e1 = __shfl(pk, j + 1, 64);
            unsigned e2 = __shfl(pk, j + 2, 64), e3 = __shfl(pk, j + 3, 64);
            unsigned v0 = in_bf[(size_t)(e0 & 0xffffu) * 64 + lane];
            unsigned v1 = in_bf[(size_t)(e1 & 0xffffu) * 64 + lane];
            unsigned v2 = in_bf[(size_t)(e2 & 0xffffu) * 64 + lane];
            unsigned v3 = in_bf[(size_t)(e3 & 0xffffu) * 64 + lane];
            float w0 = bfhi(e0), w1 = bfhi(e1), w2 = bfhi(e2), w3 = bfhi(e3);
            ax0 += w0 * bflo(v0); ay0 += w0 * bfhi(v0);
            ax1 += w1 * bflo(v1); ay1 += w1 * bfhi(v1);
            ax0 += w2 * bflo(v2); ay0 += w2 * bfhi(v2);
            ax1 += w3 * bflo(v3); ay1 += w3 * bfhi(v3);
        }
        for (; j < c; ++j) {
            unsigned e = __shfl(pk, j, 64);
            unsigned v = in_bf[(size_t)(e & 0xffffu) * 64 + lane];
            float w = bfhi(e);
            ax0 += w * bflo(v); ay0 += w * bfhi(v);
        }
    }
    out_bf[(size_t)row * 64 + lane] = cvt_pk_bf16(dr * (ax0 + ax1), dr * (ay0 + ay1));
    if (WITH_S) {
        #pragma unroll
        for (int o = 32; o >= 1; o >>= 1) wsum += __shfl_xor(wsum, o, 64);
        if (lane == 0) s_out[row] = dr * (dr + wsum);
    }
}

// ---------------- rep epilogue: rep = wu * (x + [g1|g2]@Bcat + s*bw + bb); write f32 + bf16 ----------------
__global__ __launch_bounds__(256) void k_rep_gemm(const unsigned* __restrict__ g1, const unsigned* __restrict__ g2,
                                                  const short* __restrict__ Bcat,
                                                  const float* __restrict__ xv, const float* __restrict__ xt,
                                                  const float* __restrict__ s, const float* __restrict__ bw,
                                                  const float* __restrict__ bb, const float* __restrict__ weight_u,
                                                  float* __restrict__ rep0, unsigned* __restrict__ rep_bf) {
    __shared__ short Alds[64 * 264];
    const int tid = threadIdx.x, lane = tid & 63, wid = tid >> 6;
    const int rowBase = blockIdx.x * 64;
    #pragma unroll
    for (int i = 0; i < 8; i++) {
        int cid = tid + i * 256;           // 0..2047: 64 rows x 32 chunks of 16B
        int r = cid >> 5, c = cid & 31;
        int grow = rowBase + r; if (grow >= NNODE) grow = NNODE - 1;
        const unsigned* src = (c < 16) ? (g1 + (size_t)grow * 64 + c * 4)
                                       : (g2 + (size_t)grow * 64 + (c - 16) * 4);
        uint4 v = *(const uint4*)src;
        *(uint4*)&Alds[r * 264 + c * 8] = v;
    }
    __syncthreads();
    const int fk = (lane >> 4) * 8;
    const int arow = wid * 16 + (lane & 15);
    floatx4 acc[8];
    #pragma unroll
    for (int n = 0; n < 8; n++) acc[n] = (floatx4)0.f;
    #pragma unroll
    for (int ks = 0; ks < 8; ks++) {
        short8v af = *(const short8v*)&Alds[arow * 264 + ks * 32 + fk];
        #pragma unroll
        for (int n = 0; n < 8; n++) {
            short8v bf = *(const short8v*)(Bcat + ks * 4096 + (n * 16 + (lane & 15)) * 32 + fk);
            acc[n] = __builtin_amdgcn_mfma_f32_16x16x32_bf16(af, bf, acc[n], 0, 0, 0);
        }
    }
    #pragma unroll
    for (int n = 0; n < 8; n++) {
        int col = n * 16 + (lane & 15);
        float bwc = bw[col], bbc = bb[col];
        #pragma unroll
        for (int q = 0; q < 4; q++) {
            int row = rowBase + wid * 16 + (lane >> 4) * 4 + q;
            int rc = row < NNODE ? row : NNODE - 1;
            float xval = (col < 64) ? xv[(size_t)rc * 64 + col] : xt[(size_t)rc * 64 + col - 64];
            float v = acc[n][q] + xval + s[rc] * bwc + bbc;
            float w = (rc < NUSER) ? weight_u[rc * 2 + (col >> 6)] : 1.0f;
            v *= w;
            float pn = __shfl_xor(v, 1, 64);
            if (row < NNODE) {
                rep0[(size_t)row * 128 + col] = v;
                if (!(lane & 1))
                    rep_bf[(size_t)row * 64 + n * 8 + ((lane & 15) >> 1)] = cvt_pk_bf16(v, pn);
            }
        }
    }
}

// fused: user aggregation + item-item layer 1 (both read rep_bf, independent)
#define UBLK (NUSER * 64 / 256)   // 5000
__global__ __launch_bounds__(256) void k_user_item1(const float* __restrict__ rep0, const unsigned* __restrict__ rep_bf,
                                                    const int* __restrict__ ug, const float* __restrict__ uwm,
                                                    const int* __restrict__ mm_col, const float* __restrict__ mm_values,
                                                    float* __restrict__ out, unsigned* __restrict__ tmp_bf) {
    int bid = blockIdx.x;
    if (bid < UBLK) {
        int id = bid * 256 + threadIdx.x;
        int u = id >> 6, lane = id & 63;
        float2 acc = *(const float2*)(rep0 + (size_t)u * 128 + 2 * lane);   // self, f32-exact
        #pragma unroll 4
        for (int k = 0; k < KUSER; k++) {
            int nb = ug[u * KUSER + k];
            float w = uwm[u * KUSER + k];
            unsigned v = rep_bf[(size_t)nb * 64 + lane];
            acc.x += w * bflo(v);
            acc.y += w * bfhi(v);
        }
        *(float2*)(out + (size_t)u * 128 + 2 * lane) = acc;
    } else {
        int id = (bid - UBLK) * 256 + threadIdx.x;
        int r = id >> 6, lane = id & 63;
        float ax = 0.f, ay = 0.f;
        #pragma unroll
        for (int j = 0; j < KITEM; j++) {
            int c = mm_col[r * KITEM + j];
            float w = mm_values[r * KITEM + j];
            unsigned v = rep_bf[(size_t)(NUSER + c) * 64 + lane];
            ax += w * bflo(v);
            ay += w * bfhi(v);
        }
        tmp_bf[(size_t)r * 64 + lane] = cvt_pk_bf16(ax, ay);
    }
}

// item-item layer 2: out[NUSER+r] = rep0[NUSER+r] + gather(tmp_bf)   (out = FULL out pointer)
__global__ __launch_bounds__(256) void k_item2(const float* __restrict__ rep0, const unsigned* __restrict__ tmp_bf,
                                               const int* __restrict__ mm_col, const float* __restrict__ mm_values,
                                               float* __restrict__ out) {
    int id = blockIdx.x * 256 + threadIdx.x;
    int r = id >> 6, lane = id & 63;
    if (r >= NITEM) return;
    float ax = 0.f, ay = 0.f;
    #pragma unroll
    for (int j = 0; j < KITEM; j++) {
        int c = mm_col[r * KITEM + j];
        float w = mm_values[r * KITEM + j];
        unsigned v = tmp_bf[(size_t)c * 64 + lane];
        ax += w * bflo(v);
        ay += w * bfhi(v);
    }
    float2 base = *(const float2*)(rep0 + (size_t)(NUSER + r) * 128 + 2 * lane);
    float2 o;
    o.x = base.x + ax;
    o.y = base.y + ay;
    *(float2*)(out + (size_t)(NUSER + r) * 128 + 2 * lane) = o;
}

extern "C" void kernel_launch(void* const* d_in, const int* in_sizes, int n_in,
                              void* d_out, int out_size, void* d_ws, size_t ws_size,
                              hipStream_t stream) {
    const int*   edge_index = (const int*)d_in[0];
    const float* v_feat   = (const float*)d_in[1];
    const float* t_feat   = (const float*)d_in[2];
    const float* v_pref   = (const float*)d_in[3];
    const float* t_pref   = (const float*)d_in[4];
    const float* v_mlp1_w = (const float*)d_in[5];
    const float* v_mlp1_b = (const float*)d_in[6];
    const float* v_mlp2_w = (const float*)d_in[7];
    const float* v_mlp2_b = (const float*)d_in[8];
    const float* t_mlp1_w = (const float*)d_in[9];
    const float* t_mlp1_b = (const float*)d_in[10];
    const float* t_mlp2_w = (const float*)d_in[11];
    const float* t_mlp2_b = (const float*)d_in[12];
    const float* v_conv_w = (const float*)d_in[13];
    const float* v_conv_b = (const float*)d_in[14];
    const float* t_conv_w = (const float*)d_in[15];
    const float* t_conv_b = (const float*)d_in[16];
    const float* weight_u = (const float*)d_in[17];
    const int*   user_graph = (const int*)d_in[18];
    const float* uwm      = (const float*)d_in[19];
    const int*   mm_indices = (const int*)d_in[20];
    const float* mm_values  = (const float*)d_in[21];
    float* out = (float*)d_out;

    char* wsb = (char*)d_ws;
    size_t off = 0;
    auto alloc = [&](size_t bytes) -> void* {
        void* p = wsb + off;
        off = (off + bytes + 255) & ~(size_t)255;
        return p;
    };
    int*      cnt     = (int*)     alloc(NNODE * 4);
    float*    dinv    = (float*)   alloc(NNODE * 4);
    int*      rowptr  = (int*)     alloc((NNODE + 1) * 4);
    int*      bsum    = (int*)     alloc(256 * 4);
    int*      cursor  = (int*)     alloc(NNODE * 4);
    unsigned* csr_pkd = (unsigned*)alloc((size_t)2 * NE * 4);
    short*    Btw     = (short*)   alloc((size_t)2048 * 256 * 2);
    short*    W2b     = (short*)   alloc((size_t)256 * 64 * 2);
    short*    Bcat    = (short*)   alloc((size_t)256 * 128 * 2);
    float*    bw      = (float*)   alloc(128 * 4);
    float*    bb      = (float*)   alloc(128 * 4);
    float*    svec    = (float*)   alloc(NNODE * 4);
    float*    xv      = (float*)   alloc((size_t)NNODE * DIM * 4);
    float*    xt      = (float*)   alloc((size_t)NNODE * DIM * 4);
    unsigned* x_bf    = (unsigned*)alloc((size_t)NNODE * 64 * 4);
    unsigned* g1      = (unsigned*)alloc((size_t)NNODE * 64 * 4);
    unsigned* g2      = (unsigned*)alloc((size_t)NNODE * 64 * 4);
    float*    rep0    = (float*)   alloc((size_t)NNODE * 128 * 4);
    unsigned* rep_bf  = (unsigned*)alloc((size_t)NNODE * 64 * 4);
    unsigned* tmp_bf  = (unsigned*)alloc((size_t)NITEM * 64 * 4);
    (void)ws_size; (void)n_in; (void)in_sizes; (void)out_size;

    const int* e_src = edge_index;
    const int* e_dst = edge_index + 2 * NE;
    const int* mm_col = mm_indices + NITEM * KITEM;

    const int NB = (NNODE + 255) / 256;   // 235

    // degree + dinv + packed CSR
    hipMemsetAsync(cnt, 0, NNODE * 4, stream);
    k_count<<<(2 * NE + 255) / 256, 256, 0, stream>>>(e_dst, cnt, 2 * NE);
    k_dinv<<<(NNODE + 255) / 256, 256, 0, stream>>>(cnt, dinv);
    k_scanA<<<NB, 256, 0, stream>>>(cnt, rowptr, bsum, NNODE);
    k_scanB<<<1, 256, 0, stream>>>(bsum, NB);
    k_scanC<<<NB, 256, 0, stream>>>(rowptr, bsum, cursor, NNODE);
    k_fill<<<(2 * NE + 255) / 256, 256, 0, stream>>>(e_src, e_dst, dinv, cursor, csr_pkd, 2 * NE);

    // conv-weight prep (Bcat, bw, bb)
    k_prep<<<1, 256, 0, stream>>>(v_conv_w, t_conv_w, v_conv_b, t_conv_b, Bcat, bw, bb);

    // fused MLP per branch (item rows of x)
    {
        dim3 t1(2048 / 16, 16);
        k_transpose_bf16<<<t1, 256, 0, stream>>>(v_mlp1_w, Btw, 2048, 256);
        dim3 t2(256 / 16, 4);
        k_transpose_bf16<<<t2, 256, 0, stream>>>(v_mlp2_w, W2b, 256, 64);
        mlp_fused<<<NITEM / 64, 256, 0, stream>>>(v_feat, Btw, v_mlp1_b, W2b, v_mlp2_b,
                                                  xv + (size_t)NUSER * DIM, x_bf + (size_t)NUSER * 64, 0, 2048);
        dim3 t3(768 / 16, 16);
        k_transpose_bf16<<<t3, 256, 0, stream>>>(t_mlp1_w, Btw, 768, 256);
        k_transpose_bf16<<<t2, 256, 0, stream>>>(t_mlp2_w, W2b, 256, 64);
        mlp_fused<<<NITEM / 64, 256, 0, stream>>>(t_feat, Btw, t_mlp1_b, W2b, t_mlp2_b,
                                                  xt + (size_t)NUSER * DIM, x_bf + (size_t)NUSER * 64, 32, 768);
    }
    // user rows of x
    {
        dim3 g(NUSER / 4, 2);
        k_l2n_pref<<<g, 256, 0, stream>>>(v_pref, t_pref, xv, xt, x_bf);
    }

    // two propagation hops (no conv between — linearity), then fused rep GEMM epilogue
    k_gather_p<true><<<(NNODE + 3) / 4, 256, 0, stream>>>(rowptr, csr_pkd, dinv, x_bf, g1, svec);
    k_gather_p<false><<<(NNODE + 3) / 4, 256, 0, stream>>>(rowptr, csr_pkd, dinv, g1, g2, nullptr);
    k_rep_gemm<<<(NNODE + 63) / 64, 256, 0, stream>>>(g1, g2, Bcat, xv, xt, svec, bw, bb, weight_u,
                                                      rep0, rep_bf);

    // users + item layer 1 (one grid), then item layer 2
    k_user_item1<<<UBLK + NITEM * 64 / 256, 256, 0, stream>>>(rep0, rep_bf, user_graph, uwm,
                                                              mm_col, mm_values, out, tmp_bf);
    k_item2<<<NITEM * 64 / 256, 256, 0, stream>>>(rep0, tmp_bf, mm_col, mm_values, out);
}

// Round 9
// 617.354 us; speedup vs baseline: 1.0162x; 1.0162x over previous
//
#include <hip/hip_runtime.h>

#define NUSER 20000
#define NITEM 40000
#define NNODE 60000
#define DIM   64
#define NE    1000000   // per direction; total directed edges = 2*NE
#define KUSER 40
#define KITEM 10

typedef __attribute__((ext_vector_type(8))) short short8v;
typedef __attribute__((ext_vector_type(4))) float floatx4;

__device__ inline short bf16rne(float f) {
    unsigned u = __builtin_bit_cast(unsigned, f);
    unsigned r = (u + 0x7fffu + ((u >> 16) & 1u)) >> 16;
    return (short)r;
}
__device__ inline unsigned cvt_pk_bf16(float lo, float hi) {   // dst.lo16=bf16(lo), dst.hi16=bf16(hi)
    unsigned r;
    asm("v_cvt_pk_bf16_f32 %0, %1, %2" : "=v"(r) : "v"(lo), "v"(hi));
    return r;
}
__device__ inline float bflo(unsigned v) { return __builtin_bit_cast(float, v << 16); }
__device__ inline float bfhi(unsigned v) { return __builtin_bit_cast(float, v & 0xffff0000u); }

// ---------------- degree / norm ----------------
__global__ __launch_bounds__(256) void k_count(const int* __restrict__ dst, int* __restrict__ cnt, int n) {
    int i = blockIdx.x * 256 + threadIdx.x;
    if (i < n) atomicAdd(&cnt[dst[i]], 1);
}

__global__ __launch_bounds__(256) void k_dinv(const int* __restrict__ cnt, float* __restrict__ dinv) {
    int i = blockIdx.x * 256 + threadIdx.x;
    if (i < NNODE) dinv[i] = 1.0f / sqrtf((float)(cnt[i] + 1));  // +1 self loop
}

// ---------------- exclusive scan (3-kernel) ----------------
__global__ __launch_bounds__(256) void k_scanA(const int* __restrict__ v, int* __restrict__ excl,
                                               int* __restrict__ bsum, int n) {
    __shared__ int s[256];
    int t = threadIdx.x, i = blockIdx.x * 256 + t;
    int orig = (i < n) ? v[i] : 0;
    s[t] = orig; __syncthreads();
    #pragma unroll
    for (int off = 1; off < 256; off <<= 1) {
        int u = (t >= off) ? s[t - off] : 0;
        __syncthreads();
        s[t] += u;
        __syncthreads();
    }
    if (i < n) excl[i] = s[t] - orig;
    if (t == 255) bsum[blockIdx.x] = s[255];
}

__global__ __launch_bounds__(256) void k_scanB(int* __restrict__ bsum, int nb) {
    __shared__ int s[256];
    int t = threadIdx.x;
    int orig = (t < nb) ? bsum[t] : 0;
    s[t] = orig; __syncthreads();
    #pragma unroll
    for (int off = 1; off < 256; off <<= 1) {
        int u = (t >= off) ? s[t - off] : 0;
        __syncthreads();
        s[t] += u;
        __syncthreads();
    }
    if (t < nb) bsum[t] = s[t] - orig;  // exclusive
}

__global__ __launch_bounds__(256) void k_scanC(int* __restrict__ excl, const int* __restrict__ bsum,
                                               int* __restrict__ cursor, int n) {
    int i = blockIdx.x * 256 + threadIdx.x;
    if (i < n) {
        int v = excl[i] + bsum[blockIdx.x];
        excl[i] = v;
        cursor[i] = v;
    }
    if (i == 0) excl[n] = 2 * NE;
}

// fill packed CSR: entry = (bf16bits(dinv[src]) << 16) | src   (src < 65536)
__global__ __launch_bounds__(256) void k_fill(const int* __restrict__ src, const int* __restrict__ dst,
                                              const float* __restrict__ dinv, int* __restrict__ cursor,
                                              unsigned* __restrict__ csr_pkd, int n) {
    int i = blockIdx.x * 256 + threadIdx.x;
    if (i >= n) return;
    int s = src[i], d = dst[i];
    unsigned pk = ((unsigned)(unsigned short)bf16rne(dinv[s]) << 16) | (unsigned)s;
    int pos = atomicAdd(&cursor[d], 1);
    csr_pkd[pos] = pk;
}

// ---------------- weight transpose + bf16 cast, k-blocked: Btb[k/32][n][k%32] ----------------
__global__ __launch_bounds__(256) void k_transpose_bf16(const float* __restrict__ B, short* __restrict__ Btb,
                                                        int K, int N) {
    __shared__ float s[16][17];
    int t = threadIdx.x, tx = t & 15, ty = t >> 4;
    int k0 = blockIdx.x * 16, n0 = blockIdx.y * 16;
    s[ty][tx] = B[(size_t)(k0 + ty) * N + n0 + tx];
    __syncthreads();
    int k = k0 + tx, n = n0 + ty;
    Btb[(size_t)(k >> 5) * (N * 32) + n * 32 + (k & 31)] = bf16rne(s[tx][ty]);
}

// ---------------- prep: Bcat (256x128 block-diag {Wv,Wt,Wv2,Wt2}, k-blocked bf16), bw=b@W, bb=2b ----------------
__global__ __launch_bounds__(256) void k_prep(const float* __restrict__ Wv, const float* __restrict__ Wt,
                                              const float* __restrict__ bv, const float* __restrict__ bt,
                                              short* __restrict__ Bcat, float* __restrict__ bw, float* __restrict__ bb) {
    __shared__ float Wld[2][64][65];
    __shared__ float W2ld[2][64][65];
    int t = threadIdx.x;
    for (int id = t; id < 8192; id += 256) {
        int z = id >> 12, k = (id >> 6) & 63, n = id & 63;
        Wld[z][k][n] = (z ? Wt : Wv)[k * 64 + n];
    }
    __syncthreads();
    for (int id = t; id < 8192; id += 256) {
        int z = id >> 12, k = (id >> 6) & 63, n = id & 63;
        float a = 0.f;
        #pragma unroll 8
        for (int m = 0; m < 64; m++) a += Wld[z][k][m] * Wld[z][m][n];
        W2ld[z][k][n] = a;
    }
    __syncthreads();
    for (int id = t; id < 32768; id += 256) {
        int k = id >> 7, n = id & 127;
        int kb = k >> 6, kk = k & 63;
        float v = 0.f;
        if (kb == 0)      { if (n < 64)  v = Wld[0][kk][n]; }
        else if (kb == 1) { if (n >= 64) v = Wld[1][kk][n - 64]; }
        else if (kb == 2) { if (n < 64)  v = W2ld[0][kk][n]; }
        else              { if (n >= 64) v = W2ld[1][kk][n - 64]; }
        Bcat[(k >> 5) * 4096 + n * 32 + (k & 31)] = bf16rne(v);
    }
    if (t < 128) {
        int z = t >> 6, n = t & 63;
        const float* b = z ? bt : bv;
        float a = 0.f;
        #pragma unroll 8
        for (int k = 0; k < 64; k++) a += b[k] * Wld[z][k][n];
        bw[t] = a;
        bb[t] = 2.f * b[n];
    }
}

// ---------------- fused MLP: x_bf = l2n(lrelu(A@W1+b1)@W2+b2) ----------------
// A LDS double-buffered; B read DIRECT from L2 (k-blocked layout -> contiguous 1KB fragments).
#define AP   40
#define MIDP 264
__global__ __launch_bounds__(256) void mlp_fused(const float* __restrict__ A, const short* __restrict__ B1t,
                                                 const float* __restrict__ b1, const short* __restrict__ B2t,
                                                 const float* __restrict__ b2,
                                                 unsigned* __restrict__ xbf, int boff, int K) {
    __shared__ short smem[64 * MIDP];    // 33.8 KB: phase1 uses first 2*64*AP as A dbuf; later mid[64][MIDP]
    short* As = smem;
    const int tid = threadIdx.x;
    const int lane = tid & 63, wid = tid >> 6;
    const int rowBase = blockIdx.x * 64;

    const int sar = tid >> 2, sac = (tid & 3) * 8;
    const float* aptr = A + (size_t)(rowBase + sar) * K + sac;

    const int fk = (lane >> 4) * 8;
    const int faoff = (lane & 15) * AP + fk;
    const int bcol0 = wid * 64 + (lane & 15);

    floatx4 acc[4][4];
    #pragma unroll
    for (int m = 0; m < 4; m++)
        #pragma unroll
        for (int n = 0; n < 4; n++) acc[m][n] = (floatx4)0.f;

    float4 ra0, ra1;
    const int nk = K >> 5;

    auto ldg = [&](int ks) {
        const float* ap = aptr + ks * 32;
        ra0 = *(const float4*)(ap);
        ra1 = *(const float4*)(ap + 4);
    };
    auto stv = [&](int buf) {
        uint4 av;
        av.x = cvt_pk_bf16(ra0.x, ra0.y); av.y = cvt_pk_bf16(ra0.z, ra0.w);
        av.z = cvt_pk_bf16(ra1.x, ra1.y); av.w = cvt_pk_bf16(ra1.z, ra1.w);
        *(uint4*)&As[buf * (64 * AP) + sar * AP + sac] = av;
    };

    ldg(0); stv(0);
    __syncthreads();
    int cur = 0;
    for (int ks = 0; ks < nk; ++ks) {
        if (ks + 1 < nk) ldg(ks + 1);
        short8v a[4], b[4];
        #pragma unroll
        for (int n = 0; n < 4; n++)
            b[n] = *(const short8v*)(B1t + (size_t)ks * 8192 + (bcol0 + n * 16) * 32 + fk);
        #pragma unroll
        for (int m = 0; m < 4; m++) a[m] = *(const short8v*)&As[cur * (64 * AP) + faoff + m * 16 * AP];
        #pragma unroll
        for (int m = 0; m < 4; m++)
            #pragma unroll
            for (int n = 0; n < 4; n++)
                acc[m][n] = __builtin_amdgcn_mfma_f32_16x16x32_bf16(a[m], b[n], acc[m][n], 0, 0, 0);
        if (ks + 1 < nk) stv(cur ^ 1);
        __syncthreads();
        cur ^= 1;
    }

    // phase 2: bias + lrelu -> bf16 mid in LDS (C/D layout: col=lane&15, row=(lane>>4)*4+q)
    short* mid = smem;
    float bcol[4];
    #pragma unroll
    for (int n = 0; n < 4; n++) bcol[n] = b1[wid * 64 + n * 16 + (lane & 15)];
    #pragma unroll
    for (int m = 0; m < 4; m++)
        #pragma unroll
        for (int n = 0; n < 4; n++)
            #pragma unroll
            for (int q = 0; q < 4; q++) {
                int row = m * 16 + (lane >> 4) * 4 + q;
                int col = wid * 64 + n * 16 + (lane & 15);
                float v = acc[m][n][q] + bcol[n];
                v = v > 0.f ? v : 0.01f * v;
                mid[row * MIDP + col] = bf16rne(v);
            }
    __syncthreads();

    // phase 3: temp = mid @ W2 (wave wid owns rows wid*16..wid*16+15)
    floatx4 acc2[4];
    #pragma unroll
    for (int n2 = 0; n2 < 4; n2++) acc2[n2] = (floatx4)0.f;
    const int arow = wid * 16 + (lane & 15);
    #pragma unroll
    for (int ks2 = 0; ks2 < 8; ++ks2) {
        short8v af = *(const short8v*)&mid[arow * MIDP + ks2 * 32 + fk];
        const short* bp = B2t + ks2 * 2048 + fk;
        short8v bf4[4];
        #pragma unroll
        for (int n2 = 0; n2 < 4; n2++) bf4[n2] = *(const short8v*)(bp + (n2 * 16 + (lane & 15)) * 32);
        #pragma unroll
        for (int n2 = 0; n2 < 4; n2++)
            acc2[n2] = __builtin_amdgcn_mfma_f32_16x16x32_bf16(af, bf4[n2], acc2[n2], 0, 0, 0);
    }

    // phase 4: bias + row-L2-norm, write packed bf16 x
    float b2c[4];
    #pragma unroll
    for (int n2 = 0; n2 < 4; n2++) b2c[n2] = b2[n2 * 16 + (lane & 15)];
    #pragma unroll
    for (int q = 0; q < 4; ++q) {
        float v[4]; float ss = 0.f;
        #pragma unroll
        for (int n2 = 0; n2 < 4; n2++) { v[n2] = acc2[n2][q] + b2c[n2]; ss += v[n2] * v[n2]; }
        ss += __shfl_xor(ss, 1, 64);
        ss += __shfl_xor(ss, 2, 64);
        ss += __shfl_xor(ss, 4, 64);
        ss += __shfl_xor(ss, 8, 64);
        float sc = 1.f / fmaxf(sqrtf(ss), 1e-12f);
        int grow = rowBase + wid * 16 + (lane >> 4) * 4 + q;
        #pragma unroll
        for (int n2 = 0; n2 < 4; n2++) {
            float xn = v[n2] * sc;
            float pn = __shfl_xor(xn, 1, 64);
            if (!(lane & 1))
                xbf[(size_t)grow * 64 + boff + n2 * 8 + ((lane & 15) >> 1)] = cvt_pk_bf16(xn, pn);
        }
    }
}

// ---------------- pref rows: L2-normalize -> packed bf16 ----------------
__global__ __launch_bounds__(256) void k_l2n_pref(const float* __restrict__ prefv, const float* __restrict__ preft,
                                                  unsigned* __restrict__ xbf) {
    int row = blockIdx.x * 4 + (threadIdx.x >> 6);
    int lane = threadIdx.x & 63;
    if (row >= NUSER) return;
    const float* p = blockIdx.y ? preft : prefv;
    float v = p[(size_t)row * 64 + lane];
    float ss = v * v;
    #pragma unroll
    for (int off = 32; off >= 1; off >>= 1) ss += __shfl_xor(ss, off, 64);
    float xn = v / fmaxf(sqrtf(ss), 1e-12f);
    float pn = __shfl_xor(xn, 1, 64);
    if (!(lane & 1))
        xbf[(size_t)row * 64 + (blockIdx.y ? 32 : 0) + (lane >> 1)] = cvt_pk_bf16(xn, pn);
}

// ---------------- hop 1: g1 = A_hat(x) (bf16), s = A_hat(1) ----------------
__global__ __launch_bounds__(256) void k_gather_p(const int* __restrict__ rowptr, const unsigned* __restrict__ csr_pkd,
                                                  const float* __restrict__ dinv, const unsigned* __restrict__ in_bf,
                                                  unsigned* __restrict__ out_bf, float* __restrict__ s_out) {
    int row = blockIdx.x * 4 + (threadIdx.x >> 6);
    int lane = threadIdx.x & 63;
    if (row >= NNODE) return;
    int p0 = rowptr[row], p1 = rowptr[row + 1];
    float dr = dinv[row];
    unsigned sv = in_bf[(size_t)row * 64 + lane];
    float ax0 = dr * bflo(sv), ay0 = dr * bfhi(sv);
    float ax1 = 0.f, ay1 = 0.f;
    float wsum = 0.f;
    for (int p = p0; p < p1; p += 64) {
        int c = p1 - p; if (c > 64) c = 64;
        unsigned pk = (lane < c) ? csr_pkd[p + lane] : 0u;
        wsum += bfhi(pk);
        int j = 0;
        for (; j + 4 <= c; j += 4) {
            unsigned e0 = __shfl(pk, j, 64),     e1 = __shfl(pk, j + 1, 64);
            unsigned e2 = __shfl(pk, j + 2, 64), e3 = __shfl(pk, j + 3, 64);
            unsigned v0 = in_bf[(size_t)(e0 & 0xffffu) * 64 + lane];
            unsigned v1 = in_bf[(size_t)(e1 & 0xffffu) * 64 + lane];
            unsigned v2 = in_bf[(size_t)(e2 & 0xffffu) * 64 + lane];
            unsigned v3 = in_bf[(size_t)(e3 & 0xffffu) * 64 + lane];
            float w0 = bfhi(e0), w1 = bfhi(e1), w2 = bfhi(e2), w3 = bfhi(e3);
            ax0 += w0 * bflo(v0); ay0 += w0 * bfhi(v0);
            ax1 += w1 * bflo(v1); ay1 += w1 * bfhi(v1);
            ax0 += w2 * bflo(v2); ay0 += w2 * bfhi(v2);
            ax1 += w3 * bflo(v3); ay1 += w3 * bfhi(v3);
        }
        for (; j < c; ++j) {
            unsigned e = __shfl(pk, j, 64);
            unsigned v = in_bf[(size_t)(e & 0xffffu) * 64 + lane];
            float w = bfhi(e);
            ax0 += w * bflo(v); ay0 += w * bfhi(v);
        }
    }
    out_bf[(size_t)row * 64 + lane] = cvt_pk_bf16(dr * (ax0 + ax1), dr * (ay0 + ay1));
    #pragma unroll
    for (int o = 32; o >= 1; o >>= 1) wsum += __shfl_xor(wsum, o, 64);
    if (lane == 0) s_out[row] = dr * (dr + wsum);
}

// ---------------- hop 2 fused with rep epilogue ----------------
// 8 waves x 2 rows: gather g2 rows from g1; LDS As[16][264] = [g1row | g2row] bf16 (K=256);
// then 8-wave MFMA: rep = wu * (x + [g1|g2]@Bcat + s*bw + bb); write rep0 f32 + rep_bf.
__global__ __launch_bounds__(512) void k_gather2_rep(const int* __restrict__ rowptr, const unsigned* __restrict__ csr_pkd,
                                                     const float* __restrict__ dinv, const unsigned* __restrict__ g1,
                                                     const short* __restrict__ Bcat, const unsigned* __restrict__ x_bf,
                                                     const float* __restrict__ s, const float* __restrict__ bw,
                                                     const float* __restrict__ bb, const float* __restrict__ weight_u,
                                                     float* __restrict__ rep0, unsigned* __restrict__ rep_bf) {
    __shared__ short As[16 * 264];
    const int tid = threadIdx.x, lane = tid & 63, w = tid >> 6;   // 8 waves
    const int rowBase = blockIdx.x * 16;

    for (int rr = 0; rr < 2; ++rr) {
        int lrow = w * 2 + rr;
        int row = rowBase + lrow;
        int p0 = rowptr[row], p1 = rowptr[row + 1];
        float dr = dinv[row];
        unsigned sv = g1[(size_t)row * 64 + lane];
        float ax0 = dr * bflo(sv), ay0 = dr * bfhi(sv);
        float ax1 = 0.f, ay1 = 0.f;
        for (int p = p0; p < p1; p += 64) {
            int c = p1 - p; if (c > 64) c = 64;
            unsigned pk = (lane < c) ? csr_pkd[p + lane] : 0u;
            int j = 0;
            for (; j + 4 <= c; j += 4) {
                unsigned e0 = __shfl(pk, j, 64),     e1 = __shfl(pk, j + 1, 64);
                unsigned e2 = __shfl(pk, j + 2, 64), e3 = __shfl(pk, j + 3, 64);
                unsigned v0 = g1[(size_t)(e0 & 0xffffu) * 64 + lane];
                unsigned v1 = g1[(size_t)(e1 & 0xffffu) * 64 + lane];
                unsigned v2 = g1[(size_t)(e2 & 0xffffu) * 64 + lane];
                unsigned v3 = g1[(size_t)(e3 & 0xffffu) * 64 + lane];
                float w0 = bfhi(e0), w1 = bfhi(e1), w2 = bfhi(e2), w3 = bfhi(e3);
                ax0 += w0 * bflo(v0); ay0 += w0 * bfhi(v0);
                ax1 += w1 * bflo(v1); ay1 += w1 * bfhi(v1);
                ax0 += w2 * bflo(v2); ay0 += w2 * bfhi(v2);
                ax1 += w3 * bflo(v3); ay1 += w3 * bfhi(v3);
            }
            for (; j < c; ++j) {
                unsigned e = __shfl(pk, j, 64);
                unsigned v = g1[(size_t)(e & 0xffffu) * 64 + lane];
                float wj = bfhi(e);
                ax0 += wj * bflo(v); ay0 += wj * bfhi(v);
            }
        }
        // stage K=256 row: [0..127]=g1 row (sv), [128..255]=g2 row
        *(unsigned*)&As[lrow * 264 + 2 * lane] = sv;
        *(unsigned*)&As[lrow * 264 + 128 + 2 * lane] = cvt_pk_bf16(dr * (ax0 + ax1), dr * (ay0 + ay1));
    }
    __syncthreads();

    // MFMA: wave w computes C[16][16] for cols w*16.. over K=256
    const int fk = (lane >> 4) * 8;
    floatx4 acc = (floatx4)0.f;
    #pragma unroll
    for (int ks = 0; ks < 8; ++ks) {
        short8v af = *(const short8v*)&As[(lane & 15) * 264 + ks * 32 + fk];
        short8v bf = *(const short8v*)(Bcat + ks * 4096 + (w * 16 + (lane & 15)) * 32 + fk);
        acc = __builtin_amdgcn_mfma_f32_16x16x32_bf16(af, bf, acc, 0, 0, 0);
    }
    const int col = w * 16 + (lane & 15);
    const float bwc = bw[col], bbc = bb[col];
    #pragma unroll
    for (int q = 0; q < 4; ++q) {
        int lrow = (lane >> 4) * 4 + q;
        int row = rowBase + lrow;
        unsigned xw = x_bf[(size_t)row * 64 + (col >> 1)];
        float xval = (col & 1) ? bfhi(xw) : bflo(xw);
        float v = acc[q] + xval + s[row] * bwc + bbc;
        float wu = (row < NUSER) ? weight_u[row * 2 + (col >> 6)] : 1.0f;
        v *= wu;
        rep0[(size_t)row * 128 + col] = v;
        float pn = __shfl_xor(v, 1, 64);
        if (!(lane & 1))
            rep_bf[(size_t)row * 64 + (col >> 1)] = cvt_pk_bf16(v, pn);
    }
}

// fused: user aggregation + item-item layer 1 (both read rep_bf, independent)
#define UBLK (NUSER * 64 / 256)   // 5000
__global__ __launch_bounds__(256) void k_user_item1(const float* __restrict__ rep0, const unsigned* __restrict__ rep_bf,
                                                    const int* __restrict__ ug, const float* __restrict__ uwm,
                                                    const int* __restrict__ mm_col, const float* __restrict__ mm_values,
                                                    float* __restrict__ out, unsigned* __restrict__ tmp_bf) {
    int bid = blockIdx.x;
    if (bid < UBLK) {
        int id = bid * 256 + threadIdx.x;
        int u = id >> 6, lane = id & 63;
        float2 acc = *(const float2*)(rep0 + (size_t)u * 128 + 2 * lane);   // self, f32-exact
        #pragma unroll 4
        for (int k = 0; k < KUSER; k++) {
            int nb = ug[u * KUSER + k];
            float w = uwm[u * KUSER + k];
            unsigned v = rep_bf[(size_t)nb * 64 + lane];
            acc.x += w * bflo(v);
            acc.y += w * bfhi(v);
        }
        *(float2*)(out + (size_t)u * 128 + 2 * lane) = acc;
    } else {
        int id = (bid - UBLK) * 256 + threadIdx.x;
        int r = id >> 6, lane = id & 63;
        float ax = 0.f, ay = 0.f;
        #pragma unroll
        for (int j = 0; j < KITEM; j++) {
            int c = mm_col[r * KITEM + j];
            float w = mm_values[r * KITEM + j];
            unsigned v = rep_bf[(size_t)(NUSER + c) * 64 + lane];
            ax += w * bflo(v);
            ay += w * bfhi(v);
        }
        tmp_bf[(size_t)r * 64 + lane] = cvt_pk_bf16(ax, ay);
    }
}

// item-item layer 2: out[NUSER+r] = rep0[NUSER+r] + gather(tmp_bf)   (out = FULL out pointer)
__global__ __launch_bounds__(256) void k_item2(const float* __restrict__ rep0, const unsigned* __restrict__ tmp_bf,
                                               const int* __restrict__ mm_col, const float* __restrict__ mm_values,
                                               float* __restrict__ out) {
    int id = blockIdx.x * 256 + threadIdx.x;
    int r = id >> 6, lane = id & 63;
    if (r >= NITEM) return;
    float ax = 0.f, ay = 0.f;
    #pragma unroll
    for (int j = 0; j < KITEM; j++) {
        int c = mm_col[r * KITEM + j];
        float w = mm_values[r * KITEM + j];
        unsigned v = tmp_bf[(size_t)c * 64 + lane];
        ax += w * bflo(v);
        ay += w * bfhi(v);
    }
    float2 base = *(const float2*)(rep0 + (size_t)(NUSER + r) * 128 + 2 * lane);
    float2 o;
    o.x = base.x + ax;
    o.y = base.y + ay;
    *(float2*)(out + (size_t)(NUSER + r) * 128 + 2 * lane) = o;
}

extern "C" void kernel_launch(void* const* d_in, const int* in_sizes, int n_in,
                              void* d_out, int out_size, void* d_ws, size_t ws_size,
                              hipStream_t stream) {
    const int*   edge_index = (const int*)d_in[0];
    const float* v_feat   = (const float*)d_in[1];
    const float* t_feat   = (const float*)d_in[2];
    const float* v_pref   = (const float*)d_in[3];
    const float* t_pref   = (const float*)d_in[4];
    const float* v_mlp1_w = (const float*)d_in[5];
    const float* v_mlp1_b = (const float*)d_in[6];
    const float* v_mlp2_w = (const float*)d_in[7];
    const float* v_mlp2_b = (const float*)d_in[8];
    const float* t_mlp1_w = (const float*)d_in[9];
    const float* t_mlp1_b = (const float*)d_in[10];
    const float* t_mlp2_w = (const float*)d_in[11];
    const float* t_mlp2_b = (const float*)d_in[12];
    const float* v_conv_w = (const float*)d_in[13];
    const float* v_conv_b = (const float*)d_in[14];
    const float* t_conv_w = (const float*)d_in[15];
    const float* t_conv_b = (const float*)d_in[16];
    const float* weight_u = (const float*)d_in[17];
    const int*   user_graph = (const int*)d_in[18];
    const float* uwm      = (const float*)d_in[19];
    const int*   mm_indices = (const int*)d_in[20];
    const float* mm_values  = (const float*)d_in[21];
    float* out = (float*)d_out;

    char* wsb = (char*)d_ws;
    size_t off = 0;
    auto alloc = [&](size_t bytes) -> void* {
        void* p = wsb + off;
        off = (off + bytes + 255) & ~(size_t)255;
        return p;
    };
    int*      cnt     = (int*)     alloc(NNODE * 4);
    float*    dinv    = (float*)   alloc(NNODE * 4);
    int*      rowptr  = (int*)     alloc((NNODE + 1) * 4);
    int*      bsum    = (int*)     alloc(256 * 4);
    int*      cursor  = (int*)     alloc(NNODE * 4);
    unsigned* csr_pkd = (unsigned*)alloc((size_t)2 * NE * 4);
    short*    Btw     = (short*)   alloc((size_t)2048 * 256 * 2);
    short*    W2b     = (short*)   alloc((size_t)256 * 64 * 2);
    short*    Bcat    = (short*)   alloc((size_t)256 * 128 * 2);
    float*    bw      = (float*)   alloc(128 * 4);
    float*    bb      = (float*)   alloc(128 * 4);
    float*    svec    = (float*)   alloc(NNODE * 4);
    unsigned* x_bf    = (unsigned*)alloc((size_t)NNODE * 64 * 4);
    unsigned* g1      = (unsigned*)alloc((size_t)NNODE * 64 * 4);
    float*    rep0    = (float*)   alloc((size_t)NNODE * 128 * 4);
    unsigned* rep_bf  = (unsigned*)alloc((size_t)NNODE * 64 * 4);
    unsigned* tmp_bf  = (unsigned*)alloc((size_t)NITEM * 64 * 4);
    (void)ws_size; (void)n_in; (void)in_sizes; (void)out_size;

    const int* e_src = edge_index;
    const int* e_dst = edge_index + 2 * NE;
    const int* mm_col = mm_indices + NITEM * KITEM;

    const int NB = (NNODE + 255) / 256;   // 235

    // degree + dinv + packed CSR
    hipMemsetAsync(cnt, 0, NNODE * 4, stream);
    k_count<<<(2 * NE + 255) / 256, 256, 0, stream>>>(e_dst, cnt, 2 * NE);
    k_dinv<<<(NNODE + 255) / 256, 256, 0, stream>>>(cnt, dinv);
    k_scanA<<<NB, 256, 0, stream>>>(cnt, rowptr, bsum, NNODE);
    k_scanB<<<1, 256, 0, stream>>>(bsum, NB);
    k_scanC<<<NB, 256, 0, stream>>>(rowptr, bsum, cursor, NNODE);
    k_fill<<<(2 * NE + 255) / 256, 256, 0, stream>>>(e_src, e_dst, dinv, cursor, csr_pkd, 2 * NE);

    // conv-weight prep (Bcat, bw, bb)
    k_prep<<<1, 256, 0, stream>>>(v_conv_w, t_conv_w, v_conv_b, t_conv_b, Bcat, bw, bb);

    // fused MLP per branch (item rows of x_bf)
    {
        dim3 t1(2048 / 16, 16);
        k_transpose_bf16<<<t1, 256, 0, stream>>>(v_mlp1_w, Btw, 2048, 256);
        dim3 t2(256 / 16, 4);
        k_transpose_bf16<<<t2, 256, 0, stream>>>(v_mlp2_w, W2b, 256, 64);
        mlp_fused<<<NITEM / 64, 256, 0, stream>>>(v_feat, Btw, v_mlp1_b, W2b, v_mlp2_b,
                                                  x_bf + (size_t)NUSER * 64, 0, 2048);
        dim3 t3(768 / 16, 16);
        k_transpose_bf16<<<t3, 256, 0, stream>>>(t_mlp1_w, Btw, 768, 256);
        k_transpose_bf16<<<t2, 256, 0, stream>>>(t_mlp2_w, W2b, 256, 64);
        mlp_fused<<<NITEM / 64, 256, 0, stream>>>(t_feat, Btw, t_mlp1_b, W2b, t_mlp2_b,
                                                  x_bf + (size_t)NUSER * 64, 32, 768);
    }
    // user rows of x_bf
    {
        dim3 g(NUSER / 4, 2);
        k_l2n_pref<<<g, 256, 0, stream>>>(v_pref, t_pref, x_bf);
    }

    // hop1 -> g1 + svec; hop2 fused with rep epilogue (linearity of GCN conv)
    k_gather_p<<<(NNODE + 3) / 4, 256, 0, stream>>>(rowptr, csr_pkd, dinv, x_bf, g1, svec);
    k_gather2_rep<<<NNODE / 16, 512, 0, stream>>>(rowptr, csr_pkd, dinv, g1, Bcat, x_bf,
                                                  svec, bw, bb, weight_u, rep0, rep_bf);

    // users + item layer 1 (one grid), then item layer 2
    k_user_item1<<<UBLK + NITEM * 64 / 256, 256, 0, stream>>>(rep0, rep_bf, user_graph, uwm,
                                                              mm_col, mm_values, out, tmp_bf);
    k_item2<<<NITEM * 64 / 256, 256, 0, stream>>>(rep0, tmp_bf, mm_col, mm_values, out);
}

// Round 11
// 582.415 us; speedup vs baseline: 1.0772x; 1.0600x over previous
//
#include <hip/hip_runtime.h>

#define NUSER 20000
#define NITEM 40000
#define NNODE 60000
#define DIM   64
#define NE    1000000   // pairs; directed edges = 2*NE
#define KUSER 40
#define KITEM 10

typedef __attribute__((ext_vector_type(8))) short short8v;
typedef __attribute__((ext_vector_type(4))) float floatx4;

__device__ inline short bf16rne(float f) {
    unsigned u = __builtin_bit_cast(unsigned, f);
    unsigned r = (u + 0x7fffu + ((u >> 16) & 1u)) >> 16;
    return (short)r;
}
__device__ inline unsigned cvt_pk_bf16(float lo, float hi) {
    unsigned r;
    asm("v_cvt_pk_bf16_f32 %0, %1, %2" : "=v"(r) : "v"(lo), "v"(hi));
    return r;
}
__device__ inline float bflo(unsigned v) { return __builtin_bit_cast(float, v << 16); }
__device__ inline float bfhi(unsigned v) { return __builtin_bit_cast(float, v & 0xffff0000u); }

// ---------------- degree count over pairs ----------------
__global__ __launch_bounds__(256) void k_count_pair(const int* __restrict__ uu, const int* __restrict__ it,
                                                    int* __restrict__ cnt) {
    int i = blockIdx.x * 256 + threadIdx.x;
    if (i >= NE) return;
    atomicAdd(&cnt[uu[i]], 1);
    atomicAdd(&cnt[it[i]], 1);
}

// ---------------- scanA fused with dinv ----------------
__global__ __launch_bounds__(256) void k_scanA(const int* __restrict__ v, int* __restrict__ excl,
                                               int* __restrict__ bsum, float* __restrict__ dinv, int n) {
    __shared__ int s[256];
    int t = threadIdx.x, i = blockIdx.x * 256 + t;
    int orig = (i < n) ? v[i] : 0;
    if (i < n) dinv[i] = 1.0f / sqrtf((float)(orig + 1));  // +1 self loop
    s[t] = orig; __syncthreads();
    #pragma unroll
    for (int off = 1; off < 256; off <<= 1) {
        int u = (t >= off) ? s[t - off] : 0;
        __syncthreads();
        s[t] += u;
        __syncthreads();
    }
    if (i < n) excl[i] = s[t] - orig;
    if (t == 255) bsum[blockIdx.x] = s[255];
}

__global__ __launch_bounds__(256) void k_scanB(int* __restrict__ bsum, int nb) {
    __shared__ int s[256];
    int t = threadIdx.x;
    int orig = (t < nb) ? bsum[t] : 0;
    s[t] = orig; __syncthreads();
    #pragma unroll
    for (int off = 1; off < 256; off <<= 1) {
        int u = (t >= off) ? s[t - off] : 0;
        __syncthreads();
        s[t] += u;
        __syncthreads();
    }
    if (t < nb) bsum[t] = s[t] - orig;  // exclusive
}

__global__ __launch_bounds__(256) void k_scanC(int* __restrict__ excl, const int* __restrict__ bsum,
                                               int* __restrict__ cursor, int n) {
    int i = blockIdx.x * 256 + threadIdx.x;
    if (i < n) {
        int v = excl[i] + bsum[blockIdx.x];
        excl[i] = v;
        cursor[i] = v;
    }
    if (i == 0) excl[n] = 2 * NE;
}

// ---------------- fill packed CSR from pairs ----------------
__global__ __launch_bounds__(256) void k_fill_pair(const int* __restrict__ uu, const int* __restrict__ it,
                                                   const float* __restrict__ dinv, int* __restrict__ cursor,
                                                   unsigned* __restrict__ csr_pkd) {
    int i = blockIdx.x * 256 + threadIdx.x;
    if (i >= NE) return;
    int u = uu[i], t = it[i];
    unsigned pku = ((unsigned)(unsigned short)bf16rne(dinv[u]) << 16) | (unsigned)u;
    unsigned pkt = ((unsigned)(unsigned short)bf16rne(dinv[t]) << 16) | (unsigned)t;
    int pos1 = atomicAdd(&cursor[t], 1);   // edge u -> it
    csr_pkd[pos1] = pku;
    int pos2 = atomicAdd(&cursor[u], 1);   // edge it -> u
    csr_pkd[pos2] = pkt;
}

// ---------------- all 4 weight transposes in one launch ----------------
__global__ __launch_bounds__(256) void k_transpose_all(const float* __restrict__ W1v, const float* __restrict__ W1t,
                                                       const float* __restrict__ W2v, const float* __restrict__ W2t,
                                                       short* __restrict__ Bv, short* __restrict__ Bt,
                                                       short* __restrict__ B2v, short* __restrict__ B2t) {
    __shared__ float s[16][17];
    int bid = blockIdx.x;
    const float* B; short* D; int K, N, local;
    if (bid < 2048)      { B = W1v; D = Bv;  K = 2048; N = 256; local = bid; }
    else if (bid < 2816) { B = W1t; D = Bt;  K = 768;  N = 256; local = bid - 2048; }
    else if (bid < 2880) { B = W2v; D = B2v; K = 256;  N = 64;  local = bid - 2816; }
    else                 { B = W2t; D = B2t; K = 256;  N = 64;  local = bid - 2880; }
    int ktiles = K >> 4;
    int k0 = (local % ktiles) * 16, n0 = (local / ktiles) * 16;
    int t = threadIdx.x, tx = t & 15, ty = t >> 4;
    s[ty][tx] = B[(size_t)(k0 + ty) * N + n0 + tx];
    __syncthreads();
    int k = k0 + tx, n = n0 + ty;
    D[(size_t)(k >> 5) * (N * 32) + n * 32 + (k & 31)] = bf16rne(s[tx][ty]);
}

// ---------------- prep: Bcat block-diag {Wv,Wt,Wv2,Wt2}, bw=b@W, bb=2b ----------------
__global__ __launch_bounds__(256) void k_prep(const float* __restrict__ Wv, const float* __restrict__ Wt,
                                              const float* __restrict__ bv, const float* __restrict__ bt,
                                              short* __restrict__ Bcat, float* __restrict__ bw, float* __restrict__ bb) {
    __shared__ float Wld[2][64][65];
    __shared__ float W2ld[2][64][65];
    int t = threadIdx.x;
    for (int id = t; id < 8192; id += 256) {
        int z = id >> 12, k = (id >> 6) & 63, n = id & 63;
        Wld[z][k][n] = (z ? Wt : Wv)[k * 64 + n];
    }
    __syncthreads();
    for (int id = t; id < 8192; id += 256) {
        int z = id >> 12, k = (id >> 6) & 63, n = id & 63;
        float a = 0.f;
        #pragma unroll 8
        for (int m = 0; m < 64; m++) a += Wld[z][k][m] * Wld[z][m][n];
        W2ld[z][k][n] = a;
    }
    __syncthreads();
    for (int id = t; id < 32768; id += 256) {
        int k = id >> 7, n = id & 127;
        int kb = k >> 6, kk = k & 63;
        float v = 0.f;
        if (kb == 0)      { if (n < 64)  v = Wld[0][kk][n]; }
        else if (kb == 1) { if (n >= 64) v = Wld[1][kk][n - 64]; }
        else if (kb == 2) { if (n < 64)  v = W2ld[0][kk][n]; }
        else              { if (n >= 64) v = W2ld[1][kk][n - 64]; }
        Bcat[(k >> 5) * 4096 + n * 32 + (k & 31)] = bf16rne(v);
    }
    if (t < 128) {
        int z = t >> 6, n = t & 63;
        const float* b = z ? bt : bv;
        float a = 0.f;
        #pragma unroll 8
        for (int k = 0; k < 64; k++) a += b[k] * Wld[z][k][n];
        bw[t] = a;
        bb[t] = 2.f * b[n];
    }
}

// ---------------- merged fused MLP (V blocks then T blocks), B staged through LDS ----------------
#define AP   40
#define MIDP 264
#define VBLKS (NITEM / 64)   // 625
__global__ __launch_bounds__(256) void mlp_merged(const float* __restrict__ Av, const float* __restrict__ At,
                                                  const short* __restrict__ B1v, const short* __restrict__ B1t,
                                                  const float* __restrict__ b1v, const float* __restrict__ b1t,
                                                  const short* __restrict__ B2v, const short* __restrict__ B2t,
                                                  const float* __restrict__ b2v, const float* __restrict__ b2t,
                                                  unsigned* __restrict__ xbf) {
    __shared__ short smem[2 * 64 * AP + 2 * 256 * AP];
    short* As = smem;                 // [2][64*AP]
    short* Bs = smem + 2 * 64 * AP;   // [2][256*AP]; reused as mid[64][MIDP]
    const bool isV = blockIdx.x < VBLKS;
    const float* A    = isV ? Av : At;
    const short* B1t_ = isV ? B1v : B1t;
    const float* b1   = isV ? b1v : b1t;
    const short* B2t_ = isV ? B2v : B2t;
    const float* b2   = isV ? b2v : b2t;
    const int K = isV ? 2048 : 768;
    const int boff = isV ? 0 : 32;
    const int rowBase = (isV ? blockIdx.x : blockIdx.x - VBLKS) * 64;

    const int tid = threadIdx.x;
    const int lane = tid & 63, wid = tid >> 6;
    const int sar = tid >> 2, sac = (tid & 3) * 8;
    const float* aptr = A + (size_t)(rowBase + sar) * K + sac;

    const int fk = (lane >> 4) * 8;
    const int faoff = (lane & 15) * AP + fk;
    const int fboff = (wid * 64 + (lane & 15)) * AP + fk;

    floatx4 acc[4][4];
    #pragma unroll
    for (int m = 0; m < 4; m++)
        #pragma unroll
        for (int n = 0; n < 4; n++) acc[m][n] = (floatx4)0.f;

    float4 ra0, ra1;
    short8v rb[4];
    const int nk = K >> 5;

    auto ldg = [&](int ks) {
        const float* ap = aptr + ks * 32;
        ra0 = *(const float4*)(ap);
        ra1 = *(const float4*)(ap + 4);
        const short* bsrc = B1t_ + (size_t)ks * 8192 + tid * 8;
        #pragma unroll
        for (int it = 0; it < 4; it++) rb[it] = *(const short8v*)(bsrc + it * 2048);
    };
    auto stv = [&](int buf) {
        uint4 av;
        av.x = cvt_pk_bf16(ra0.x, ra0.y); av.y = cvt_pk_bf16(ra0.z, ra0.w);
        av.z = cvt_pk_bf16(ra1.x, ra1.y); av.w = cvt_pk_bf16(ra1.z, ra1.w);
        *(uint4*)&As[buf * (64 * AP) + sar * AP + sac] = av;
        #pragma unroll
        for (int it = 0; it < 4; it++)
            *(short8v*)&Bs[buf * (256 * AP) + (sar + it * 64) * AP + sac] = rb[it];
    };

    ldg(0); stv(0);
    __syncthreads();
    int cur = 0;
    for (int ks = 0; ks < nk; ++ks) {
        if (ks + 1 < nk) ldg(ks + 1);
        short8v a[4], b[4];
        #pragma unroll
        for (int m = 0; m < 4; m++) a[m] = *(const short8v*)&As[cur * (64 * AP) + faoff + m * 16 * AP];
        #pragma unroll
        for (int n = 0; n < 4; n++) b[n] = *(const short8v*)&Bs[cur * (256 * AP) + fboff + n * 16 * AP];
        #pragma unroll
        for (int m = 0; m < 4; m++)
            #pragma unroll
            for (int n = 0; n < 4; n++)
                acc[m][n] = __builtin_amdgcn_mfma_f32_16x16x32_bf16(a[m], b[n], acc[m][n], 0, 0, 0);
        if (ks + 1 < nk) stv(cur ^ 1);
        __syncthreads();
        cur ^= 1;
    }

    // phase 2: bias + lrelu -> bf16 mid in LDS
    short* mid = Bs;
    float bcol[4];
    #pragma unroll
    for (int n = 0; n < 4; n++) bcol[n] = b1[wid * 64 + n * 16 + (lane & 15)];
    #pragma unroll
    for (int m = 0; m < 4; m++)
        #pragma unroll
        for (int n = 0; n < 4; n++)
            #pragma unroll
            for (int q = 0; q < 4; q++) {
                int row = m * 16 + (lane >> 4) * 4 + q;
                int col = wid * 64 + n * 16 + (lane & 15);
                float v = acc[m][n][q] + bcol[n];
                v = v > 0.f ? v : 0.01f * v;
                mid[row * MIDP + col] = bf16rne(v);
            }
    __syncthreads();

    // phase 3: temp = mid @ W2
    floatx4 acc2[4];
    #pragma unroll
    for (int n2 = 0; n2 < 4; n2++) acc2[n2] = (floatx4)0.f;
    const int arow = wid * 16 + (lane & 15);
    #pragma unroll
    for (int ks2 = 0; ks2 < 8; ++ks2) {
        short8v af = *(const short8v*)&mid[arow * MIDP + ks2 * 32 + fk];
        const short* bp = B2t_ + ks2 * 2048 + fk;
        short8v bf4[4];
        #pragma unroll
        for (int n2 = 0; n2 < 4; n2++) bf4[n2] = *(const short8v*)(bp + (n2 * 16 + (lane & 15)) * 32);
        #pragma unroll
        for (int n2 = 0; n2 < 4; n2++)
            acc2[n2] = __builtin_amdgcn_mfma_f32_16x16x32_bf16(af, bf4[n2], acc2[n2], 0, 0, 0);
    }

    // phase 4: bias + row-L2-norm, write packed bf16 x
    float b2c[4];
    #pragma unroll
    for (int n2 = 0; n2 < 4; n2++) b2c[n2] = b2[n2 * 16 + (lane & 15)];
    #pragma unroll
    for (int q = 0; q < 4; ++q) {
        float v[4]; float ss = 0.f;
        #pragma unroll
        for (int n2 = 0; n2 < 4; n2++) { v[n2] = acc2[n2][q] + b2c[n2]; ss += v[n2] * v[n2]; }
        ss += __shfl_xor(ss, 1, 64);
        ss += __shfl_xor(ss, 2, 64);
        ss += __shfl_xor(ss, 4, 64);
        ss += __shfl_xor(ss, 8, 64);
        float sc = 1.f / fmaxf(sqrtf(ss), 1e-12f);
        int grow = NUSER + rowBase + wid * 16 + (lane >> 4) * 4 + q;
        #pragma unroll
        for (int n2 = 0; n2 < 4; n2++) {
            float xn = v[n2] * sc;
            float pn = __shfl_xor(xn, 1, 64);
            if (!(lane & 1))
                xbf[(size_t)grow * 64 + boff + n2 * 8 + ((lane & 15) >> 1)] = cvt_pk_bf16(xn, pn);
        }
    }
}

// ---------------- pref rows: L2-normalize -> packed bf16 ----------------
__global__ __launch_bounds__(256) void k_l2n_pref(const float* __restrict__ prefv, const float* __restrict__ preft,
                                                  unsigned* __restrict__ xbf) {
    int row = blockIdx.x * 4 + (threadIdx.x >> 6);
    int lane = threadIdx.x & 63;
    if (row >= NUSER) return;
    const float* p = blockIdx.y ? preft : prefv;
    float v = p[(size_t)row * 64 + lane];
    float ss = v * v;
    #pragma unroll
    for (int off = 32; off >= 1; off >>= 1) ss += __shfl_xor(ss, off, 64);
    float xn = v / fmaxf(sqrtf(ss), 1e-12f);
    float pn = __shfl_xor(xn, 1, 64);
    if (!(lane & 1))
        xbf[(size_t)row * 64 + (blockIdx.y ? 32 : 0) + (lane >> 1)] = cvt_pk_bf16(xn, pn);
}

// ---------------- hop 1: g1 = A_hat(x) (bf16), s = A_hat(1)  [R9-proven all-lane loop] ----------------
__global__ __launch_bounds__(256) void k_gather_p(const int* __restrict__ rowptr, const unsigned* __restrict__ csr_pkd,
                                                  const float* __restrict__ dinv, const unsigned* __restrict__ in_bf,
                                                  unsigned* __restrict__ out_bf, float* __restrict__ s_out) {
    int row = blockIdx.x * 4 + (threadIdx.x >> 6);
    int lane = threadIdx.x & 63;
    if (row >= NNODE) return;
    int p0 = rowptr[row], p1 = rowptr[row + 1];
    float dr = dinv[row];
    unsigned sv = in_bf[(size_t)row * 64 + lane];
    float ax0 = dr * bflo(sv), ay0 = dr * bfhi(sv);
    float ax1 = 0.f, ay1 = 0.f;
    float wsum = 0.f;
    for (int p = p0; p < p1; p += 64) {
        int c = p1 - p; if (c > 64) c = 64;
        unsigned pk = (lane < c) ? csr_pkd[p + lane] : 0u;
        wsum += bfhi(pk);
        int j = 0;
        for (; j + 4 <= c; j += 4) {
            unsigned e0 = __shfl(pk, j, 64),     e1 = __shfl(pk, j + 1, 64);
            unsigned e2 = __shfl(pk, j + 2, 64), e3 = __shfl(pk, j + 3, 64);
            unsigned v0 = in_bf[(size_t)(e0 & 0xffffu) * 64 + lane];
            unsigned v1 = in_bf[(size_t)(e1 & 0xffffu) * 64 + lane];
            unsigned v2 = in_bf[(size_t)(e2 & 0xffffu) * 64 + lane];
            unsigned v3 = in_bf[(size_t)(e3 & 0xffffu) * 64 + lane];
            float w0 = bfhi(e0), w1 = bfhi(e1), w2 = bfhi(e2), w3 = bfhi(e3);
            ax0 += w0 * bflo(v0); ay0 += w0 * bfhi(v0);
            ax1 += w1 * bflo(v1); ay1 += w1 * bfhi(v1);
            ax0 += w2 * bflo(v2); ay0 += w2 * bfhi(v2);
            ax1 += w3 * bflo(v3); ay1 += w3 * bfhi(v3);
        }
        for (; j < c; ++j) {
            unsigned e = __shfl(pk, j, 64);
            unsigned v = in_bf[(size_t)(e & 0xffffu) * 64 + lane];
            float w = bfhi(e);
            ax0 += w * bflo(v); ay0 += w * bfhi(v);
        }
    }
    out_bf[(size_t)row * 64 + lane] = cvt_pk_bf16(dr * (ax0 + ax1), dr * (ay0 + ay1));
    #pragma unroll
    for (int o = 32; o >= 1; o >>= 1) wsum += __shfl_xor(wsum, o, 64);
    if (lane == 0) s_out[row] = dr * (dr + wsum);
}

// ---------------- hop 2 fused with rep epilogue [R9-proven gather core] ----------------
__global__ __launch_bounds__(512) void k_gather2_rep(const int* __restrict__ rowptr, const unsigned* __restrict__ csr_pkd,
                                                     const float* __restrict__ dinv, const unsigned* __restrict__ g1,
                                                     const short* __restrict__ Bcat, const unsigned* __restrict__ x_bf,
                                                     const float* __restrict__ s, const float* __restrict__ bw,
                                                     const float* __restrict__ bb, const float* __restrict__ weight_u,
                                                     float* __restrict__ rep0, unsigned* __restrict__ rep_bf) {
    __shared__ short As[16 * 264];
    const int tid = threadIdx.x, lane = tid & 63, w = tid >> 6;   // 8 waves
    const int rowBase = blockIdx.x * 16;

    for (int rr = 0; rr < 2; ++rr) {
        int lrow = w * 2 + rr;
        int row = rowBase + lrow;
        int p0 = rowptr[row], p1 = rowptr[row + 1];
        float dr = dinv[row];
        unsigned sv = g1[(size_t)row * 64 + lane];
        float ax0 = dr * bflo(sv), ay0 = dr * bfhi(sv);
        float ax1 = 0.f, ay1 = 0.f;
        for (int p = p0; p < p1; p += 64) {
            int c = p1 - p; if (c > 64) c = 64;
            unsigned pk = (lane < c) ? csr_pkd[p + lane] : 0u;
            int j = 0;
            for (; j + 4 <= c; j += 4) {
                unsigned e0 = __shfl(pk, j, 64),     e1 = __shfl(pk, j + 1, 64);
                unsigned e2 = __shfl(pk, j + 2, 64), e3 = __shfl(pk, j + 3, 64);
                unsigned v0 = g1[(size_t)(e0 & 0xffffu) * 64 + lane];
                unsigned v1 = g1[(size_t)(e1 & 0xffffu) * 64 + lane];
                unsigned v2 = g1[(size_t)(e2 & 0xffffu) * 64 + lane];
                unsigned v3 = g1[(size_t)(e3 & 0xffffu) * 64 + lane];
                float w0 = bfhi(e0), w1 = bfhi(e1), w2 = bfhi(e2), w3 = bfhi(e3);
                ax0 += w0 * bflo(v0); ay0 += w0 * bfhi(v0);
                ax1 += w1 * bflo(v1); ay1 += w1 * bfhi(v1);
                ax0 += w2 * bflo(v2); ay0 += w2 * bfhi(v2);
                ax1 += w3 * bflo(v3); ay1 += w3 * bfhi(v3);
            }
            for (; j < c; ++j) {
                unsigned e = __shfl(pk, j, 64);
                unsigned v = g1[(size_t)(e & 0xffffu) * 64 + lane];
                float wj = bfhi(e);
                ax0 += wj * bflo(v); ay0 += wj * bfhi(v);
            }
        }
        // stage K=256 row: [0..127]=g1 row (sv), [128..255]=g2 row
        *(unsigned*)&As[lrow * 264 + 2 * lane] = sv;
        *(unsigned*)&As[lrow * 264 + 128 + 2 * lane] = cvt_pk_bf16(dr * (ax0 + ax1), dr * (ay0 + ay1));
    }
    __syncthreads();

    // MFMA: wave w computes C[16][16] for cols w*16.. over K=256
    const int fk = (lane >> 4) * 8;
    floatx4 acc = (floatx4)0.f;
    #pragma unroll
    for (int ks = 0; ks < 8; ++ks) {
        short8v af = *(const short8v*)&As[(lane & 15) * 264 + ks * 32 + fk];
        short8v bf = *(const short8v*)(Bcat + ks * 4096 + (w * 16 + (lane & 15)) * 32 + fk);
        acc = __builtin_amdgcn_mfma_f32_16x16x32_bf16(af, bf, acc, 0, 0, 0);
    }
    const int col = w * 16 + (lane & 15);
    const float bwc = bw[col], bbc = bb[col];
    #pragma unroll
    for (int q = 0; q < 4; ++q) {
        int lrow = (lane >> 4) * 4 + q;
        int row = rowBase + lrow;
        unsigned xw = x_bf[(size_t)row * 64 + (col >> 1)];
        float xval = (col & 1) ? bfhi(xw) : bflo(xw);
        float v = acc[q] + xval + s[row] * bwc + bbc;
        float wu = (row < NUSER) ? weight_u[row * 2 + (col >> 6)] : 1.0f;
        v *= wu;
        rep0[(size_t)row * 128 + col] = v;
        float pn = __shfl_xor(v, 1, 64);
        if (!(lane & 1))
            rep_bf[(size_t)row * 64 + (col >> 1)] = cvt_pk_bf16(v, pn);
    }
}

// fused: user aggregation + item-item layer 1
#define UBLK (NUSER * 64 / 256)   // 5000
__global__ __launch_bounds__(256) void k_user_item1(const float* __restrict__ rep0, const unsigned* __restrict__ rep_bf,
                                                    const int* __restrict__ ug, const float* __restrict__ uwm,
                                                    const int* __restrict__ mm_col, const float* __restrict__ mm_values,
                                                    float* __restrict__ out, unsigned* __restrict__ tmp_bf) {
    int bid = blockIdx.x;
    if (bid < UBLK) {
        int id = bid * 256 + threadIdx.x;
        int u = id >> 6, lane = id & 63;
        float2 acc = *(const float2*)(rep0 + (size_t)u * 128 + 2 * lane);   // self, f32-exact
        #pragma unroll 4
        for (int k = 0; k < KUSER; k++) {
            int nb = ug[u * KUSER + k];
            float w = uwm[u * KUSER + k];
            unsigned v = rep_bf[(size_t)nb * 64 + lane];
            acc.x += w * bflo(v);
            acc.y += w * bfhi(v);
        }
        *(float2*)(out + (size_t)u * 128 + 2 * lane) = acc;
    } else {
        int id = (bid - UBLK) * 256 + threadIdx.x;
        int r = id >> 6, lane = id & 63;
        float ax = 0.f, ay = 0.f;
        #pragma unroll
        for (int j = 0; j < KITEM; j++) {
            int c = mm_col[r * KITEM + j];
            float w = mm_values[r * KITEM + j];
            unsigned v = rep_bf[(size_t)(NUSER + c) * 64 + lane];
            ax += w * bflo(v);
            ay += w * bfhi(v);
        }
        tmp_bf[(size_t)r * 64 + lane] = cvt_pk_bf16(ax, ay);
    }
}

// item-item layer 2: out[NUSER+r] = rep0[NUSER+r] + gather(tmp_bf)
__global__ __launch_bounds__(256) void k_item2(const float* __restrict__ rep0, const unsigned* __restrict__ tmp_bf,
                                               const int* __restrict__ mm_col, const float* __restrict__ mm_values,
                                               float* __restrict__ out) {
    int id = blockIdx.x * 256 + threadIdx.x;
    int r = id >> 6, lane = id & 63;
    if (r >= NITEM) return;
    float ax = 0.f, ay = 0.f;
    #pragma unroll
    for (int j = 0; j < KITEM; j++) {
        int c = mm_col[r * KITEM + j];
        float w = mm_values[r * KITEM + j];
        unsigned v = tmp_bf[(size_t)c * 64 + lane];
        ax += w * bflo(v);
        ay += w * bfhi(v);
    }
    float2 base = *(const float2*)(rep0 + (size_t)(NUSER + r) * 128 + 2 * lane);
    float2 o;
    o.x = base.x + ax;
    o.y = base.y + ay;
    *(float2*)(out + (size_t)(NUSER + r) * 128 + 2 * lane) = o;
}

extern "C" void kernel_launch(void* const* d_in, const int* in_sizes, int n_in,
                              void* d_out, int out_size, void* d_ws, size_t ws_size,
                              hipStream_t stream) {
    const int*   edge_index = (const int*)d_in[0];
    const float* v_feat   = (const float*)d_in[1];
    const float* t_feat   = (const float*)d_in[2];
    const float* v_pref   = (const float*)d_in[3];
    const float* t_pref   = (const float*)d_in[4];
    const float* v_mlp1_w = (const float*)d_in[5];
    const float* v_mlp1_b = (const float*)d_in[6];
    const float* v_mlp2_w = (const float*)d_in[7];
    const float* v_mlp2_b = (const float*)d_in[8];
    const float* t_mlp1_w = (const float*)d_in[9];
    const float* t_mlp1_b = (const float*)d_in[10];
    const float* t_mlp2_w = (const float*)d_in[11];
    const float* t_mlp2_b = (const float*)d_in[12];
    const float* v_conv_w = (const float*)d_in[13];
    const float* v_conv_b = (const float*)d_in[14];
    const float* t_conv_w = (const float*)d_in[15];
    const float* t_conv_b = (const float*)d_in[16];
    const float* weight_u = (const float*)d_in[17];
    const int*   user_graph = (const int*)d_in[18];
    const float* uwm      = (const float*)d_in[19];
    const int*   mm_indices = (const int*)d_in[20];
    const float* mm_values  = (const float*)d_in[21];
    float* out = (float*)d_out;

    char* wsb = (char*)d_ws;
    size_t off = 0;
    auto alloc = [&](size_t bytes) -> void* {
        void* p = wsb + off;
        off = (off + bytes + 255) & ~(size_t)255;
        return p;
    };
    int*      cnt     = (int*)     alloc(NNODE * 4);
    float*    dinv    = (float*)   alloc(NNODE * 4);
    int*      rowptr  = (int*)     alloc((NNODE + 1) * 4);
    int*      bsum    = (int*)     alloc(256 * 4);
    int*      cursor  = (int*)     alloc(NNODE * 4);
    unsigned* csr_pkd = (unsigned*)alloc((size_t)2 * NE * 4);
    short*    Btw_v   = (short*)   alloc((size_t)2048 * 256 * 2);
    short*    Btw_t   = (short*)   alloc((size_t)768 * 256 * 2);
    short*    W2b_v   = (short*)   alloc((size_t)256 * 64 * 2);
    short*    W2b_t   = (short*)   alloc((size_t)256 * 64 * 2);
    short*    Bcat    = (short*)   alloc((size_t)256 * 128 * 2);
    float*    bw      = (float*)   alloc(128 * 4);
    float*    bb      = (float*)   alloc(128 * 4);
    float*    svec    = (float*)   alloc(NNODE * 4);
    unsigned* x_bf    = (unsigned*)alloc((size_t)NNODE * 64 * 4);
    unsigned* g1      = (unsigned*)alloc((size_t)NNODE * 64 * 4);
    float*    rep0    = (float*)   alloc((size_t)NNODE * 128 * 4);
    unsigned* rep_bf  = (unsigned*)alloc((size_t)NNODE * 64 * 4);
    unsigned* tmp_bf  = (unsigned*)alloc((size_t)NITEM * 64 * 4);
    (void)ws_size; (void)n_in; (void)in_sizes; (void)out_size;

    const int* pairs_u  = edge_index;            // edge_index[0][0..NE)   = u
    const int* pairs_it = edge_index + NE;       // edge_index[0][NE..2NE) = it
    const int* mm_col = mm_indices + NITEM * KITEM;

    const int NB = (NNODE + 255) / 256;   // 235

    // degree + dinv + packed CSR (mirror-pair structure)
    hipMemsetAsync(cnt, 0, NNODE * 4, stream);
    k_count_pair<<<(NE + 255) / 256, 256, 0, stream>>>(pairs_u, pairs_it, cnt);
    k_scanA<<<NB, 256, 0, stream>>>(cnt, rowptr, bsum, dinv, NNODE);
    k_scanB<<<1, 256, 0, stream>>>(bsum, NB);
    k_scanC<<<NB, 256, 0, stream>>>(rowptr, bsum, cursor, NNODE);
    k_fill_pair<<<(NE + 255) / 256, 256, 0, stream>>>(pairs_u, pairs_it, dinv, cursor, csr_pkd);

    // weight prep
    k_prep<<<1, 256, 0, stream>>>(v_conv_w, t_conv_w, v_conv_b, t_conv_b, Bcat, bw, bb);
    k_transpose_all<<<2944, 256, 0, stream>>>(v_mlp1_w, t_mlp1_w, v_mlp2_w, t_mlp2_w,
                                              Btw_v, Btw_t, W2b_v, W2b_t);

    // merged V+T MLP (item rows of x_bf), then user rows
    mlp_merged<<<2 * VBLKS, 256, 0, stream>>>(v_feat, t_feat, Btw_v, Btw_t, v_mlp1_b, t_mlp1_b,
                                              W2b_v, W2b_t, v_mlp2_b, t_mlp2_b, x_bf);
    {
        dim3 g(NUSER / 4, 2);
        k_l2n_pref<<<g, 256, 0, stream>>>(v_pref, t_pref, x_bf);
    }

    // hop1 -> g1 + svec; hop2 fused with rep epilogue (linearity of GCN conv)
    k_gather_p<<<(NNODE + 3) / 4, 256, 0, stream>>>(rowptr, csr_pkd, dinv, x_bf, g1, svec);
    k_gather2_rep<<<NNODE / 16, 512, 0, stream>>>(rowptr, csr_pkd, dinv, g1, Bcat, x_bf,
                                                  svec, bw, bb, weight_u, rep0, rep_bf);

    // users + item layer 1 (one grid), then item layer 2
    k_user_item1<<<UBLK + NITEM * 64 / 256, 256, 0, stream>>>(rep0, rep_bf, user_graph, uwm,
                                                              mm_col, mm_values, out, tmp_bf);
    k_item2<<<NITEM * 64 / 256, 256, 0, stream>>>(rep0, tmp_bf, mm_col, mm_values, out);
}

// Round 12
// 567.012 us; speedup vs baseline: 1.1064x; 1.0272x over previous
//
#include <hip/hip_runtime.h>

#define NUSER 20000
#define NITEM 40000
#define NNODE 60000
#define DIM   64
#define NE    1000000   // pairs; directed edges = 2*NE
#define KUSER 40
#define KITEM 10

typedef __attribute__((ext_vector_type(8))) short short8v;
typedef __attribute__((ext_vector_type(4))) float floatx4;

__device__ inline short bf16rne(float f) {
    unsigned u = __builtin_bit_cast(unsigned, f);
    unsigned r = (u + 0x7fffu + ((u >> 16) & 1u)) >> 16;
    return (short)r;
}
__device__ inline unsigned cvt_pk_bf16(float lo, float hi) {
    unsigned r;
    asm("v_cvt_pk_bf16_f32 %0, %1, %2" : "=v"(r) : "v"(lo), "v"(hi));
    return r;
}
__device__ inline float bflo(unsigned v) { return __builtin_bit_cast(float, v << 16); }
__device__ inline float bfhi(unsigned v) { return __builtin_bit_cast(float, v & 0xffff0000u); }

// ---------------- degree count over pairs ----------------
__global__ __launch_bounds__(256) void k_count_pair(const int* __restrict__ uu, const int* __restrict__ it,
                                                    int* __restrict__ cnt) {
    int i = blockIdx.x * 256 + threadIdx.x;
    if (i >= NE) return;
    atomicAdd(&cnt[uu[i]], 1);
    atomicAdd(&cnt[it[i]], 1);
}

// ---------------- scanA fused with dinv ----------------
__global__ __launch_bounds__(256) void k_scanA(const int* __restrict__ v, int* __restrict__ excl,
                                               int* __restrict__ bsum, float* __restrict__ dinv, int n) {
    __shared__ int s[256];
    int t = threadIdx.x, i = blockIdx.x * 256 + t;
    int orig = (i < n) ? v[i] : 0;
    if (i < n) dinv[i] = 1.0f / sqrtf((float)(orig + 1));  // +1 self loop
    s[t] = orig; __syncthreads();
    #pragma unroll
    for (int off = 1; off < 256; off <<= 1) {
        int u = (t >= off) ? s[t - off] : 0;
        __syncthreads();
        s[t] += u;
        __syncthreads();
    }
    if (i < n) excl[i] = s[t] - orig;
    if (t == 255) bsum[blockIdx.x] = s[255];
}

__global__ __launch_bounds__(256) void k_scanB(int* __restrict__ bsum, int nb) {
    __shared__ int s[256];
    int t = threadIdx.x;
    int orig = (t < nb) ? bsum[t] : 0;
    s[t] = orig; __syncthreads();
    #pragma unroll
    for (int off = 1; off < 256; off <<= 1) {
        int u = (t >= off) ? s[t - off] : 0;
        __syncthreads();
        s[t] += u;
        __syncthreads();
    }
    if (t < nb) bsum[t] = s[t] - orig;  // exclusive
}

__global__ __launch_bounds__(256) void k_scanC(int* __restrict__ excl, const int* __restrict__ bsum,
                                               int* __restrict__ cursor, int n) {
    int i = blockIdx.x * 256 + threadIdx.x;
    if (i < n) {
        int v = excl[i] + bsum[blockIdx.x];
        excl[i] = v;
        cursor[i] = v;
    }
    if (i == 0) excl[n] = 2 * NE;
}

// ---------------- fill packed CSR from pairs ----------------
__global__ __launch_bounds__(256) void k_fill_pair(const int* __restrict__ uu, const int* __restrict__ it,
                                                   const float* __restrict__ dinv, int* __restrict__ cursor,
                                                   unsigned* __restrict__ csr_pkd) {
    int i = blockIdx.x * 256 + threadIdx.x;
    if (i >= NE) return;
    int u = uu[i], t = it[i];
    unsigned pku = ((unsigned)(unsigned short)bf16rne(dinv[u]) << 16) | (unsigned)u;
    unsigned pkt = ((unsigned)(unsigned short)bf16rne(dinv[t]) << 16) | (unsigned)t;
    int pos1 = atomicAdd(&cursor[t], 1);   // edge u -> it
    csr_pkd[pos1] = pku;
    int pos2 = atomicAdd(&cursor[u], 1);   // edge it -> u
    csr_pkd[pos2] = pkt;
}

// ---------------- all 4 weight transposes in one launch ----------------
__global__ __launch_bounds__(256) void k_transpose_all(const float* __restrict__ W1v, const float* __restrict__ W1t,
                                                       const float* __restrict__ W2v, const float* __restrict__ W2t,
                                                       short* __restrict__ Bv, short* __restrict__ Bt,
                                                       short* __restrict__ B2v, short* __restrict__ B2t) {
    __shared__ float s[16][17];
    int bid = blockIdx.x;
    const float* B; short* D; int K, N, local;
    if (bid < 2048)      { B = W1v; D = Bv;  K = 2048; N = 256; local = bid; }
    else if (bid < 2816) { B = W1t; D = Bt;  K = 768;  N = 256; local = bid - 2048; }
    else if (bid < 2880) { B = W2v; D = B2v; K = 256;  N = 64;  local = bid - 2816; }
    else                 { B = W2t; D = B2t; K = 256;  N = 64;  local = bid - 2880; }
    int ktiles = K >> 4;
    int k0 = (local % ktiles) * 16, n0 = (local / ktiles) * 16;
    int t = threadIdx.x, tx = t & 15, ty = t >> 4;
    s[ty][tx] = B[(size_t)(k0 + ty) * N + n0 + tx];
    __syncthreads();
    int k = k0 + tx, n = n0 + ty;
    D[(size_t)(k >> 5) * (N * 32) + n * 32 + (k & 31)] = bf16rne(s[tx][ty]);
}

// ---------------- prep: Bcat block-diag {Wv,Wt,Wv2,Wt2}, bw=b@W, bb=2b ----------------
__global__ __launch_bounds__(256) void k_prep(const float* __restrict__ Wv, const float* __restrict__ Wt,
                                              const float* __restrict__ bv, const float* __restrict__ bt,
                                              short* __restrict__ Bcat, float* __restrict__ bw, float* __restrict__ bb) {
    __shared__ float Wld[2][64][65];
    __shared__ float W2ld[2][64][65];
    int t = threadIdx.x;
    for (int id = t; id < 8192; id += 256) {
        int z = id >> 12, k = (id >> 6) & 63, n = id & 63;
        Wld[z][k][n] = (z ? Wt : Wv)[k * 64 + n];
    }
    __syncthreads();
    for (int id = t; id < 8192; id += 256) {
        int z = id >> 12, k = (id >> 6) & 63, n = id & 63;
        float a = 0.f;
        #pragma unroll 8
        for (int m = 0; m < 64; m++) a += Wld[z][k][m] * Wld[z][m][n];
        W2ld[z][k][n] = a;
    }
    __syncthreads();
    for (int id = t; id < 32768; id += 256) {
        int k = id >> 7, n = id & 127;
        int kb = k >> 6, kk = k & 63;
        float v = 0.f;
        if (kb == 0)      { if (n < 64)  v = Wld[0][kk][n]; }
        else if (kb == 1) { if (n >= 64) v = Wld[1][kk][n - 64]; }
        else if (kb == 2) { if (n < 64)  v = W2ld[0][kk][n]; }
        else              { if (n >= 64) v = W2ld[1][kk][n - 64]; }
        Bcat[(k >> 5) * 4096 + n * 32 + (k & 31)] = bf16rne(v);
    }
    if (t < 128) {
        int z = t >> 6, n = t & 63;
        const float* b = z ? bt : bv;
        float a = 0.f;
        #pragma unroll 8
        for (int k = 0; k < 64; k++) a += b[k] * Wld[z][k][n];
        bw[t] = a;
        bb[t] = 2.f * b[n];
    }
}

// ---------------- merged fused MLP, 128-row tile, 8 waves ----------------
#define AP   40
#define MIDP 264
#define MBLK 128
#define VBLKS ((NITEM + MBLK - 1) / MBLK)   // 313
__global__ __launch_bounds__(512, 4) void mlp_merged(const float* __restrict__ Av, const float* __restrict__ At,
                                                  const short* __restrict__ B1v, const short* __restrict__ B1t,
                                                  const float* __restrict__ b1v, const float* __restrict__ b1t,
                                                  const short* __restrict__ B2v, const short* __restrict__ B2t,
                                                  const float* __restrict__ b2v, const float* __restrict__ b2t,
                                                  unsigned* __restrict__ xbf) {
    __shared__ short smem[MBLK * MIDP];          // 67.6 KB; phase1: A dbuf + B dbuf; later mid[128][264]
    short* As = smem;                            // [2][128*AP]
    short* Bs = smem + 2 * MBLK * AP;            // [2][256*AP]
    const bool isV = blockIdx.x < VBLKS;
    const float* A    = isV ? Av : At;
    const short* B1t_ = isV ? B1v : B1t;
    const float* b1   = isV ? b1v : b1t;
    const short* B2t_ = isV ? B2v : B2t;
    const float* b2   = isV ? b2v : b2t;
    const int K = isV ? 2048 : 768;
    const int boff = isV ? 0 : 32;
    const int rowBase = (isV ? blockIdx.x : blockIdx.x - VBLKS) * MBLK;

    const int tid = threadIdx.x;                 // 0..511
    const int lane = tid & 63, wid = tid >> 6;   // 8 waves
    const int wr = wid >> 2, wc = wid & 3;       // 2 x 4 wave grid, each 64x64

    // A stage: thread -> row tid>>2 (0..127), k-chunk (tid&3)*8
    const int sar = tid >> 2, sac = (tid & 3) * 8;
    int aclamp = rowBase + sar; if (aclamp > NITEM - 1) aclamp = NITEM - 1;
    const float* aptr = A + (size_t)aclamp * K + sac;

    const int fk = (lane >> 4) * 8;
    const int faoff = (wr * 64 + (lane & 15)) * AP + fk;
    const int fboff = (wc * 64 + (lane & 15)) * AP + fk;

    floatx4 acc[4][4];
    #pragma unroll
    for (int m = 0; m < 4; m++)
        #pragma unroll
        for (int n = 0; n < 4; n++) acc[m][n] = (floatx4)0.f;

    float4 ra0, ra1;
    short8v rb0, rb1;
    const int nk = K >> 5;

    auto ldg = [&](int ks) {
        const float* ap = aptr + ks * 32;
        ra0 = *(const float4*)(ap);
        ra1 = *(const float4*)(ap + 4);
        const short* bsrc = B1t_ + (size_t)ks * 8192 + tid * 16;   // 512 thr x 32B = 16KB/step
        rb0 = *(const short8v*)(bsrc);
        rb1 = *(const short8v*)(bsrc + 8);
    };
    auto stv = [&](int buf) {
        uint4 av;
        av.x = cvt_pk_bf16(ra0.x, ra0.y); av.y = cvt_pk_bf16(ra0.z, ra0.w);
        av.z = cvt_pk_bf16(ra1.x, ra1.y); av.w = cvt_pk_bf16(ra1.z, ra1.w);
        *(uint4*)&As[buf * (MBLK * AP) + sar * AP + sac] = av;
        // B: thread covers n = tid>>1, k' = (tid&1)*16 .. +15
        short* bd = &Bs[buf * (256 * AP) + (tid >> 1) * AP + (tid & 1) * 16];
        *(short8v*)(bd) = rb0;
        *(short8v*)(bd + 8) = rb1;
    };

    ldg(0); stv(0);
    __syncthreads();
    int cur = 0;
    for (int ks = 0; ks < nk; ++ks) {
        if (ks + 1 < nk) ldg(ks + 1);
        short8v a[4], b[4];
        #pragma unroll
        for (int m = 0; m < 4; m++) a[m] = *(const short8v*)&As[cur * (MBLK * AP) + faoff + m * 16 * AP];
        #pragma unroll
        for (int n = 0; n < 4; n++) b[n] = *(const short8v*)&Bs[cur * (256 * AP) + fboff + n * 16 * AP];
        #pragma unroll
        for (int m = 0; m < 4; m++)
            #pragma unroll
            for (int n = 0; n < 4; n++)
                acc[m][n] = __builtin_amdgcn_mfma_f32_16x16x32_bf16(a[m], b[n], acc[m][n], 0, 0, 0);
        if (ks + 1 < nk) stv(cur ^ 1);
        __syncthreads();
        cur ^= 1;
    }

    // phase 2: bias + lrelu -> bf16 mid in LDS, PACKED pair stores (even lanes)
    unsigned* mid32 = (unsigned*)smem;           // [128][132]
    float bcol[4];
    #pragma unroll
    for (int n = 0; n < 4; n++) bcol[n] = b1[wc * 64 + n * 16 + (lane & 15)];
    #pragma unroll
    for (int m = 0; m < 4; m++)
        #pragma unroll
        for (int n = 0; n < 4; n++) {
            int col = wc * 64 + n * 16 + (lane & 15);
            #pragma unroll
            for (int q = 0; q < 4; q++) {
                int row = wr * 64 + m * 16 + (lane >> 4) * 4 + q;
                float v = acc[m][n][q] + bcol[n];
                v = v > 0.f ? v : 0.01f * v;
                float pn = __shfl_xor(v, 1, 64);
                if (!(lane & 1)) mid32[row * 132 + (col >> 1)] = cvt_pk_bf16(v, pn);
            }
        }
    __syncthreads();

    // phase 3: temp = mid @ W2 (wave wid owns rows wid*16..wid*16+15 of 128)
    const short* mid = smem;
    floatx4 acc2[4];
    #pragma unroll
    for (int n2 = 0; n2 < 4; n2++) acc2[n2] = (floatx4)0.f;
    const int arow = wid * 16 + (lane & 15);
    #pragma unroll
    for (int ks2 = 0; ks2 < 8; ++ks2) {
        short8v af = *(const short8v*)&mid[arow * MIDP + ks2 * 32 + fk];
        const short* bp = B2t_ + ks2 * 2048 + fk;
        short8v bf4[4];
        #pragma unroll
        for (int n2 = 0; n2 < 4; n2++) bf4[n2] = *(const short8v*)(bp + (n2 * 16 + (lane & 15)) * 32);
        #pragma unroll
        for (int n2 = 0; n2 < 4; n2++)
            acc2[n2] = __builtin_amdgcn_mfma_f32_16x16x32_bf16(af, bf4[n2], acc2[n2], 0, 0, 0);
    }

    // phase 4: bias + row-L2-norm, write packed bf16 x
    float b2c[4];
    #pragma unroll
    for (int n2 = 0; n2 < 4; n2++) b2c[n2] = b2[n2 * 16 + (lane & 15)];
    #pragma unroll
    for (int q = 0; q < 4; ++q) {
        float v[4]; float ss = 0.f;
        #pragma unroll
        for (int n2 = 0; n2 < 4; n2++) { v[n2] = acc2[n2][q] + b2c[n2]; ss += v[n2] * v[n2]; }
        ss += __shfl_xor(ss, 1, 64);
        ss += __shfl_xor(ss, 2, 64);
        ss += __shfl_xor(ss, 4, 64);
        ss += __shfl_xor(ss, 8, 64);
        float sc = 1.f / fmaxf(sqrtf(ss), 1e-12f);
        int lr = wid * 16 + (lane >> 4) * 4 + q;
        int grow = NUSER + rowBase + lr;
        bool ok = (rowBase + lr) < NITEM;
        #pragma unroll
        for (int n2 = 0; n2 < 4; n2++) {
            float xn = v[n2] * sc;
            float pn = __shfl_xor(xn, 1, 64);
            if (ok && !(lane & 1))
                xbf[(size_t)grow * 64 + boff + n2 * 8 + ((lane & 15) >> 1)] = cvt_pk_bf16(xn, pn);
        }
    }
}

// ---------------- pref rows: L2-normalize -> packed bf16 ----------------
__global__ __launch_bounds__(256) void k_l2n_pref(const float* __restrict__ prefv, const float* __restrict__ preft,
                                                  unsigned* __restrict__ xbf) {
    int row = blockIdx.x * 4 + (threadIdx.x >> 6);
    int lane = threadIdx.x & 63;
    if (row >= NUSER) return;
    const float* p = blockIdx.y ? preft : prefv;
    float v = p[(size_t)row * 64 + lane];
    float ss = v * v;
    #pragma unroll
    for (int off = 32; off >= 1; off >>= 1) ss += __shfl_xor(ss, off, 64);
    float xn = v / fmaxf(sqrtf(ss), 1e-12f);
    float pn = __shfl_xor(xn, 1, 64);
    if (!(lane & 1))
        xbf[(size_t)row * 64 + (blockIdx.y ? 32 : 0) + (lane >> 1)] = cvt_pk_bf16(xn, pn);
}

// ---------------- hop 1: g1 = A_hat(x) (bf16), s = A_hat(1) ----------------
__global__ __launch_bounds__(256) void k_gather_p(const int* __restrict__ rowptr, const unsigned* __restrict__ csr_pkd,
                                                  const float* __restrict__ dinv, const unsigned* __restrict__ in_bf,
                                                  unsigned* __restrict__ out_bf, float* __restrict__ s_out) {
    int row = blockIdx.x * 4 + (threadIdx.x >> 6);
    int lane = threadIdx.x & 63;
    if (row >= NNODE) return;
    int p0 = rowptr[row], p1 = rowptr[row + 1];
    float dr = dinv[row];
    unsigned sv = in_bf[(size_t)row * 64 + lane];
    float ax0 = dr * bflo(sv), ay0 = dr * bfhi(sv);
    float ax1 = 0.f, ay1 = 0.f;
    float wsum = 0.f;
    for (int p = p0; p < p1; p += 64) {
        int c = p1 - p; if (c > 64) c = 64;
        unsigned pk = (lane < c) ? csr_pkd[p + lane] : 0u;
        wsum += bfhi(pk);
        int j = 0;
        for (; j + 4 <= c; j += 4) {
            unsigned e0 = __shfl(pk, j, 64),     e1 = __shfl(pk, j + 1, 64);
            unsigned e2 = __shfl(pk, j + 2, 64), e3 = __shfl(pk, j + 3, 64);
            unsigned v0 = in_bf[(size_t)(e0 & 0xffffu) * 64 + lane];
            unsigned v1 = in_bf[(size_t)(e1 & 0xffffu) * 64 + lane];
            unsigned v2 = in_bf[(size_t)(e2 & 0xffffu) * 64 + lane];
            unsigned v3 = in_bf[(size_t)(e3 & 0xffffu) * 64 + lane];
            float w0 = bfhi(e0), w1 = bfhi(e1), w2 = bfhi(e2), w3 = bfhi(e3);
            ax0 += w0 * bflo(v0); ay0 += w0 * bfhi(v0);
            ax1 += w1 * bflo(v1); ay1 += w1 * bfhi(v1);
            ax0 += w2 * bflo(v2); ay0 += w2 * bfhi(v2);
            ax1 += w3 * bflo(v3); ay1 += w3 * bfhi(v3);
        }
        for (; j < c; ++j) {
            unsigned e = __shfl(pk, j, 64);
            unsigned v = in_bf[(size_t)(e & 0xffffu) * 64 + lane];
            float w = bfhi(e);
            ax0 += w * bflo(v); ay0 += w * bfhi(v);
        }
    }
    out_bf[(size_t)row * 64 + lane] = cvt_pk_bf16(dr * (ax0 + ax1), dr * (ay0 + ay1));
    #pragma unroll
    for (int o = 32; o >= 1; o >>= 1) wsum += __shfl_xor(wsum, o, 64);
    if (lane == 0) s_out[row] = dr * (dr + wsum);
}

// ---------------- hop 2 fused with rep epilogue ----------------
__global__ __launch_bounds__(512) void k_gather2_rep(const int* __restrict__ rowptr, const unsigned* __restrict__ csr_pkd,
                                                     const float* __restrict__ dinv, const unsigned* __restrict__ g1,
                                                     const short* __restrict__ Bcat, const unsigned* __restrict__ x_bf,
                                                     const float* __restrict__ s, const float* __restrict__ bw,
                                                     const float* __restrict__ bb, const float* __restrict__ weight_u,
                                                     float* __restrict__ rep0, unsigned* __restrict__ rep_bf) {
    __shared__ short As[16 * 264];
    const int tid = threadIdx.x, lane = tid & 63, w = tid >> 6;   // 8 waves
    const int rowBase = blockIdx.x * 16;

    for (int rr = 0; rr < 2; ++rr) {
        int lrow = w * 2 + rr;
        int row = rowBase + lrow;
        int p0 = rowptr[row], p1 = rowptr[row + 1];
        float dr = dinv[row];
        unsigned sv = g1[(size_t)row * 64 + lane];
        float ax0 = dr * bflo(sv), ay0 = dr * bfhi(sv);
        float ax1 = 0.f, ay1 = 0.f;
        for (int p = p0; p < p1; p += 64) {
            int c = p1 - p; if (c > 64) c = 64;
            unsigned pk = (lane < c) ? csr_pkd[p + lane] : 0u;
            int j = 0;
            for (; j + 4 <= c; j += 4) {
                unsigned e0 = __shfl(pk, j, 64),     e1 = __shfl(pk, j + 1, 64);
                unsigned e2 = __shfl(pk, j + 2, 64), e3 = __shfl(pk, j + 3, 64);
                unsigned v0 = g1[(size_t)(e0 & 0xffffu) * 64 + lane];
                unsigned v1 = g1[(size_t)(e1 & 0xffffu) * 64 + lane];
                unsigned v2 = g1[(size_t)(e2 & 0xffffu) * 64 + lane];
                unsigned v3 = g1[(size_t)(e3 & 0xffffu) * 64 + lane];
                float w0 = bfhi(e0), w1 = bfhi(e1), w2 = bfhi(e2), w3 = bfhi(e3);
                ax0 += w0 * bflo(v0); ay0 += w0 * bfhi(v0);
                ax1 += w1 * bflo(v1); ay1 += w1 * bfhi(v1);
                ax0 += w2 * bflo(v2); ay0 += w2 * bfhi(v2);
                ax1 += w3 * bflo(v3); ay1 += w3 * bfhi(v3);
            }
            for (; j < c; ++j) {
                unsigned e = __shfl(pk, j, 64);
                unsigned v = g1[(size_t)(e & 0xffffu) * 64 + lane];
                float wj = bfhi(e);
                ax0 += wj * bflo(v); ay0 += wj * bfhi(v);
            }
        }
        // stage K=256 row: [0..127]=g1 row (sv), [128..255]=g2 row
        *(unsigned*)&As[lrow * 264 + 2 * lane] = sv;
        *(unsigned*)&As[lrow * 264 + 128 + 2 * lane] = cvt_pk_bf16(dr * (ax0 + ax1), dr * (ay0 + ay1));
    }
    __syncthreads();

    // MFMA: wave w computes C[16][16] for cols w*16.. over K=256
    const int fk = (lane >> 4) * 8;
    floatx4 acc = (floatx4)0.f;
    #pragma unroll
    for (int ks = 0; ks < 8; ++ks) {
        short8v af = *(const short8v*)&As[(lane & 15) * 264 + ks * 32 + fk];
        short8v bf = *(const short8v*)(Bcat + ks * 4096 + (w * 16 + (lane & 15)) * 32 + fk);
        acc = __builtin_amdgcn_mfma_f32_16x16x32_bf16(af, bf, acc, 0, 0, 0);
    }
    const int col = w * 16 + (lane & 15);
    const float bwc = bw[col], bbc = bb[col];
    #pragma unroll
    for (int q = 0; q < 4; ++q) {
        int lrow = (lane >> 4) * 4 + q;
        int row = rowBase + lrow;
        unsigned xw = x_bf[(size_t)row * 64 + (col >> 1)];
        float xval = (col & 1) ? bfhi(xw) : bflo(xw);
        float v = acc[q] + xval + s[row] * bwc + bbc;
        float wu = (row < NUSER) ? weight_u[row * 2 + (col >> 6)] : 1.0f;
        v *= wu;
        rep0[(size_t)row * 128 + col] = v;
        float pn = __shfl_xor(v, 1, 64);
        if (!(lane & 1))
            rep_bf[(size_t)row * 64 + (col >> 1)] = cvt_pk_bf16(v, pn);
    }
}

// fused: user aggregation + item-item layer 1
#define UBLK (NUSER * 64 / 256)   // 5000
__global__ __launch_bounds__(256) void k_user_item1(const float* __restrict__ rep0, const unsigned* __restrict__ rep_bf,
                                                    const int* __restrict__ ug, const float* __restrict__ uwm,
                                                    const int* __restrict__ mm_col, const float* __restrict__ mm_values,
                                                    float* __restrict__ out, unsigned* __restrict__ tmp_bf) {
    int bid = blockIdx.x;
    if (bid < UBLK) {
        int id = bid * 256 + threadIdx.x;
        int u = id >> 6, lane = id & 63;
        float2 acc = *(const float2*)(rep0 + (size_t)u * 128 + 2 * lane);   // self, f32-exact
        #pragma unroll 4
        for (int k = 0; k < KUSER; k++) {
            int nb = ug[u * KUSER + k];
            float w = uwm[u * KUSER + k];
            unsigned v = rep_bf[(size_t)nb * 64 + lane];
            acc.x += w * bflo(v);
            acc.y += w * bfhi(v);
        }
        *(float2*)(out + (size_t)u * 128 + 2 * lane) = acc;
    } else {
        int id = (bid - UBLK) * 256 + threadIdx.x;
        int r = id >> 6, lane = id & 63;
        float ax = 0.f, ay = 0.f;
        #pragma unroll
        for (int j = 0; j < KITEM; j++) {
            int c = mm_col[r * KITEM + j];
            float w = mm_values[r * KITEM + j];
            unsigned v = rep_bf[(size_t)(NUSER + c) * 64 + lane];
            ax += w * bflo(v);
            ay += w * bfhi(v);
        }
        tmp_bf[(size_t)r * 64 + lane] = cvt_pk_bf16(ax, ay);
    }
}

// item-item layer 2: out[NUSER+r] = rep0[NUSER+r] + gather(tmp_bf)
__global__ __launch_bounds__(256) void k_item2(const float* __restrict__ rep0, const unsigned* __restrict__ tmp_bf,
                                               const int* __restrict__ mm_col, const float* __restrict__ mm_values,
                                               float* __restrict__ out) {
    int id = blockIdx.x * 256 + threadIdx.x;
    int r = id >> 6, lane = id & 63;
    if (r >= NITEM) return;
    float ax = 0.f, ay = 0.f;
    #pragma unroll
    for (int j = 0; j < KITEM; j++) {
        int c = mm_col[r * KITEM + j];
        float w = mm_values[r * KITEM + j];
        unsigned v = tmp_bf[(size_t)c * 64 + lane];
        ax += w * bflo(v);
        ay += w * bfhi(v);
    }
    float2 base = *(const float2*)(rep0 + (size_t)(NUSER + r) * 128 + 2 * lane);
    float2 o;
    o.x = base.x + ax;
    o.y = base.y + ay;
    *(float2*)(out + (size_t)(NUSER + r) * 128 + 2 * lane) = o;
}

extern "C" void kernel_launch(void* const* d_in, const int* in_sizes, int n_in,
                              void* d_out, int out_size, void* d_ws, size_t ws_size,
                              hipStream_t stream) {
    const int*   edge_index = (const int*)d_in[0];
    const float* v_feat   = (const float*)d_in[1];
    const float* t_feat   = (const float*)d_in[2];
    const float* v_pref   = (const float*)d_in[3];
    const float* t_pref   = (const float*)d_in[4];
    const float* v_mlp1_w = (const float*)d_in[5];
    const float* v_mlp1_b = (const float*)d_in[6];
    const float* v_mlp2_w = (const float*)d_in[7];
    const float* v_mlp2_b = (const float*)d_in[8];
    const float* t_mlp1_w = (const float*)d_in[9];
    const float* t_mlp1_b = (const float*)d_in[10];
    const float* t_mlp2_w = (const float*)d_in[11];
    const float* t_mlp2_b = (const float*)d_in[12];
    const float* v_conv_w = (const float*)d_in[13];
    const float* v_conv_b = (const float*)d_in[14];
    const float* t_conv_w = (const float*)d_in[15];
    const float* t_conv_b = (const float*)d_in[16];
    const float* weight_u = (const float*)d_in[17];
    const int*   user_graph = (const int*)d_in[18];
    const float* uwm      = (const float*)d_in[19];
    const int*   mm_indices = (const int*)d_in[20];
    const float* mm_values  = (const float*)d_in[21];
    float* out = (float*)d_out;

    char* wsb = (char*)d_ws;
    size_t off = 0;
    auto alloc = [&](size_t bytes) -> void* {
        void* p = wsb + off;
        off = (off + bytes + 255) & ~(size_t)255;
        return p;
    };
    int*      cnt     = (int*)     alloc(NNODE * 4);
    float*    dinv    = (float*)   alloc(NNODE * 4);
    int*      rowptr  = (int*)     alloc((NNODE + 1) * 4);
    int*      bsum    = (int*)     alloc(256 * 4);
    int*      cursor  = (int*)     alloc(NNODE * 4);
    unsigned* csr_pkd = (unsigned*)alloc((size_t)2 * NE * 4);
    short*    Btw_v   = (short*)   alloc((size_t)2048 * 256 * 2);
    short*    Btw_t   = (short*)   alloc((size_t)768 * 256 * 2);
    short*    W2b_v   = (short*)   alloc((size_t)256 * 64 * 2);
    short*    W2b_t   = (short*)   alloc((size_t)256 * 64 * 2);
    short*    Bcat    = (short*)   alloc((size_t)256 * 128 * 2);
    float*    bw      = (float*)   alloc(128 * 4);
    float*    bb      = (float*)   alloc(128 * 4);
    float*    svec    = (float*)   alloc(NNODE * 4);
    unsigned* x_bf    = (unsigned*)alloc((size_t)NNODE * 64 * 4);
    unsigned* g1      = (unsigned*)alloc((size_t)NNODE * 64 * 4);
    float*    rep0    = (float*)   alloc((size_t)NNODE * 128 * 4);
    unsigned* rep_bf  = (unsigned*)alloc((size_t)NNODE * 64 * 4);
    unsigned* tmp_bf  = (unsigned*)alloc((size_t)NITEM * 64 * 4);
    (void)ws_size; (void)n_in; (void)in_sizes; (void)out_size;

    const int* pairs_u  = edge_index;            // edge_index[0][0..NE)   = u
    const int* pairs_it = edge_index + NE;       // edge_index[0][NE..2NE) = it
    const int* mm_col = mm_indices + NITEM * KITEM;

    const int NB = (NNODE + 255) / 256;   // 235

    // degree + dinv + packed CSR (mirror-pair structure)
    hipMemsetAsync(cnt, 0, NNODE * 4, stream);
    k_count_pair<<<(NE + 255) / 256, 256, 0, stream>>>(pairs_u, pairs_it, cnt);
    k_scanA<<<NB, 256, 0, stream>>>(cnt, rowptr, bsum, dinv, NNODE);
    k_scanB<<<1, 256, 0, stream>>>(bsum, NB);
    k_scanC<<<NB, 256, 0, stream>>>(rowptr, bsum, cursor, NNODE);
    k_fill_pair<<<(NE + 255) / 256, 256, 0, stream>>>(pairs_u, pairs_it, dinv, cursor, csr_pkd);

    // weight prep
    k_prep<<<1, 256, 0, stream>>>(v_conv_w, t_conv_w, v_conv_b, t_conv_b, Bcat, bw, bb);
    k_transpose_all<<<2944, 256, 0, stream>>>(v_mlp1_w, t_mlp1_w, v_mlp2_w, t_mlp2_w,
                                              Btw_v, Btw_t, W2b_v, W2b_t);

    // merged V+T MLP (item rows of x_bf), then user rows
    mlp_merged<<<2 * VBLKS, 512, 0, stream>>>(v_feat, t_feat, Btw_v, Btw_t, v_mlp1_b, t_mlp1_b,
                                              W2b_v, W2b_t, v_mlp2_b, t_mlp2_b, x_bf);
    {
        dim3 g(NUSER / 4, 2);
        k_l2n_pref<<<g, 256, 0, stream>>>(v_pref, t_pref, x_bf);
    }

    // hop1 -> g1 + svec; hop2 fused with rep epilogue (linearity of GCN conv)
    k_gather_p<<<(NNODE + 3) / 4, 256, 0, stream>>>(rowptr, csr_pkd, dinv, x_bf, g1, svec);
    k_gather2_rep<<<NNODE / 16, 512, 0, stream>>>(rowptr, csr_pkd, dinv, g1, Bcat, x_bf,
                                                  svec, bw, bb, weight_u, rep0, rep_bf);

    // users + item layer 1 (one grid), then item layer 2
    k_user_item1<<<UBLK + NITEM * 64 / 256, 256, 0, stream>>>(rep0, rep_bf, user_graph, uwm,
                                                              mm_col, mm_values, out, tmp_bf);
    k_item2<<<NITEM * 64 / 256, 256, 0, stream>>>(rep0, tmp_bf, mm_col, mm_values, out);
}

// Round 13
// 559.056 us; speedup vs baseline: 1.1222x; 1.0142x over previous
//
#include <hip/hip_runtime.h>

#define NUSER 20000
#define NITEM 40000
#define NNODE 60000
#define DIM   64
#define NE    1000000   // pairs; directed edges = 2*NE
#define KUSER 40
#define KITEM 10

typedef __attribute__((ext_vector_type(8))) short short8v;
typedef __attribute__((ext_vector_type(4))) float floatx4;

__device__ inline short bf16rne(float f) {
    unsigned u = __builtin_bit_cast(unsigned, f);
    unsigned r = (u + 0x7fffu + ((u >> 16) & 1u)) >> 16;
    return (short)r;
}
__device__ inline unsigned cvt_pk_bf16(float lo, float hi) {
    unsigned r;
    asm("v_cvt_pk_bf16_f32 %0, %1, %2" : "=v"(r) : "v"(lo), "v"(hi));
    return r;
}
__device__ inline float bflo(unsigned v) { return __builtin_bit_cast(float, v << 16); }
__device__ inline float bfhi(unsigned v) { return __builtin_bit_cast(float, v & 0xffff0000u); }

// ================= mega A: degree count (pairs) + all 4 weight transposes =================
#define CNTB ((NE + 255) / 256)        // 3907
#define TRB  2944
__global__ __launch_bounds__(256) void k_count_transpose(const int* __restrict__ uu, const int* __restrict__ it,
                                                         int* __restrict__ cnt,
                                                         const float* __restrict__ W1v, const float* __restrict__ W1t,
                                                         const float* __restrict__ W2v, const float* __restrict__ W2t,
                                                         short* __restrict__ Bv, short* __restrict__ Bt,
                                                         short* __restrict__ B2v, short* __restrict__ B2t) {
    __shared__ float s[16][17];
    int bid = blockIdx.x;
    if (bid < CNTB) {
        int i = bid * 256 + threadIdx.x;
        if (i >= NE) return;
        atomicAdd(&cnt[uu[i]], 1);
        atomicAdd(&cnt[it[i]], 1);
        return;
    }
    bid -= CNTB;
    const float* B; short* D; int K, N, local;
    if (bid < 2048)      { B = W1v; D = Bv;  K = 2048; N = 256; local = bid; }
    else if (bid < 2816) { B = W1t; D = Bt;  K = 768;  N = 256; local = bid - 2048; }
    else if (bid < 2880) { B = W2v; D = B2v; K = 256;  N = 64;  local = bid - 2816; }
    else                 { B = W2t; D = B2t; K = 256;  N = 64;  local = bid - 2880; }
    int ktiles = K >> 4;
    int k0 = (local % ktiles) * 16, n0 = (local / ktiles) * 16;
    int t = threadIdx.x, tx = t & 15, ty = t >> 4;
    s[ty][tx] = B[(size_t)(k0 + ty) * N + n0 + tx];
    __syncthreads();
    int k = k0 + tx, n = n0 + ty;
    D[(size_t)(k >> 5) * (N * 32) + n * 32 + (k & 31)] = bf16rne(s[tx][ty]);
}

// ---------------- scanA fused with dinv ----------------
__global__ __launch_bounds__(256) void k_scanA(const int* __restrict__ v, int* __restrict__ excl,
                                               int* __restrict__ bsum, float* __restrict__ dinv, int n) {
    __shared__ int s[256];
    int t = threadIdx.x, i = blockIdx.x * 256 + t;
    int orig = (i < n) ? v[i] : 0;
    if (i < n) dinv[i] = 1.0f / sqrtf((float)(orig + 1));  // +1 self loop
    s[t] = orig; __syncthreads();
    #pragma unroll
    for (int off = 1; off < 256; off <<= 1) {
        int u = (t >= off) ? s[t - off] : 0;
        __syncthreads();
        s[t] += u;
        __syncthreads();
    }
    if (i < n) excl[i] = s[t] - orig;
    if (t == 255) bsum[blockIdx.x] = s[255];
}

// ================= scanB (block 0) + conv-weight prep (block 1) =================
__global__ __launch_bounds__(256) void k_scanB_prep(int* __restrict__ bsum, int nb,
                                                    const float* __restrict__ Wv, const float* __restrict__ Wt,
                                                    const float* __restrict__ bv, const float* __restrict__ bt,
                                                    short* __restrict__ Bcat, float* __restrict__ bw,
                                                    float* __restrict__ bb) {
    __shared__ float Wld[2][64][65];
    __shared__ float W2ld[2][64][65];
    int t = threadIdx.x;
    if (blockIdx.x == 0) {
        int* s = (int*)&Wld[0][0][0];
        int orig = (t < nb) ? bsum[t] : 0;
        s[t] = orig; __syncthreads();
        #pragma unroll
        for (int off = 1; off < 256; off <<= 1) {
            int u = (t >= off) ? s[t - off] : 0;
            __syncthreads();
            s[t] += u;
            __syncthreads();
        }
        if (t < nb) bsum[t] = s[t] - orig;  // exclusive
        return;
    }
    for (int id = t; id < 8192; id += 256) {
        int z = id >> 12, k = (id >> 6) & 63, n = id & 63;
        Wld[z][k][n] = (z ? Wt : Wv)[k * 64 + n];
    }
    __syncthreads();
    for (int id = t; id < 8192; id += 256) {
        int z = id >> 12, k = (id >> 6) & 63, n = id & 63;
        float a = 0.f;
        #pragma unroll 8
        for (int m = 0; m < 64; m++) a += Wld[z][k][m] * Wld[z][m][n];
        W2ld[z][k][n] = a;
    }
    __syncthreads();
    for (int id = t; id < 32768; id += 256) {
        int k = id >> 7, n = id & 127;
        int kb = k >> 6, kk = k & 63;
        float v = 0.f;
        if (kb == 0)      { if (n < 64)  v = Wld[0][kk][n]; }
        else if (kb == 1) { if (n >= 64) v = Wld[1][kk][n - 64]; }
        else if (kb == 2) { if (n < 64)  v = W2ld[0][kk][n]; }
        else              { if (n >= 64) v = W2ld[1][kk][n - 64]; }
        Bcat[(k >> 5) * 4096 + n * 32 + (k & 31)] = bf16rne(v);
    }
    if (t < 128) {
        int z = t >> 6, n = t & 63;
        const float* b = z ? bt : bv;
        float a = 0.f;
        #pragma unroll 8
        for (int k = 0; k < 64; k++) a += b[k] * Wld[z][k][n];
        bw[t] = a;
        bb[t] = 2.f * b[n];
    }
}

__global__ __launch_bounds__(256) void k_scanC(int* __restrict__ excl, const int* __restrict__ bsum,
                                               int* __restrict__ cursor, int n) {
    int i = blockIdx.x * 256 + threadIdx.x;
    if (i < n) {
        int v = excl[i] + bsum[blockIdx.x];
        excl[i] = v;
        cursor[i] = v;
    }
    if (i == 0) excl[n] = 2 * NE;
}

// ================= mega B: CSR fill + merged MLP + pref L2-norm =================
#define AP   40
#define MIDP 264
#define MBLK 128
#define VBLKS ((NITEM + MBLK - 1) / MBLK)   // 313
#define FILLB ((NE + 511) / 512)            // 1954
#define MLPB  (2 * VBLKS)                   // 626
#define L2NB  (NUSER * 2 / 8)               // 5000 (8 waves/block, 1 row-branch per wave)
__global__ __launch_bounds__(512, 4) void k_fill_mlp_l2n(
        const int* __restrict__ uu, const int* __restrict__ it, const float* __restrict__ dinv,
        int* __restrict__ cursor, unsigned* __restrict__ csr_pkd,
        const float* __restrict__ Av, const float* __restrict__ At,
        const short* __restrict__ B1v, const short* __restrict__ B1t,
        const float* __restrict__ b1v, const float* __restrict__ b1t,
        const short* __restrict__ B2v, const short* __restrict__ B2t,
        const float* __restrict__ b2v, const float* __restrict__ b2t,
        const float* __restrict__ prefv, const float* __restrict__ preft,
        unsigned* __restrict__ xbf) {
    __shared__ short smem[MBLK * MIDP];          // 67.6 KB
    const int tid = threadIdx.x;
    int bid = blockIdx.x;

    if (bid < FILLB) {                           // ---- CSR fill ----
        int i = bid * 512 + tid;
        if (i >= NE) return;
        int u = uu[i], t = it[i];
        unsigned pku = ((unsigned)(unsigned short)bf16rne(dinv[u]) << 16) | (unsigned)u;
        unsigned pkt = ((unsigned)(unsigned short)bf16rne(dinv[t]) << 16) | (unsigned)t;
        int pos1 = atomicAdd(&cursor[t], 1);
        csr_pkd[pos1] = pku;
        int pos2 = atomicAdd(&cursor[u], 1);
        csr_pkd[pos2] = pkt;
        return;
    }
    bid -= FILLB;

    if (bid >= MLPB) {                           // ---- pref rows L2-norm ----
        int lb = bid - MLPB;
        int lane = tid & 63;
        int wg = lb * 8 + (tid >> 6);            // 0..39999
        int row = wg >> 1, br = wg & 1;
        if (row >= NUSER) return;
        const float* p = br ? preft : prefv;
        float v = p[(size_t)row * 64 + lane];
        float ss = v * v;
        #pragma unroll
        for (int off = 32; off >= 1; off >>= 1) ss += __shfl_xor(ss, off, 64);
        float xn = v / fmaxf(sqrtf(ss), 1e-12f);
        float pn = __shfl_xor(xn, 1, 64);
        if (!(lane & 1))
            xbf[(size_t)row * 64 + (br ? 32 : 0) + (lane >> 1)] = cvt_pk_bf16(xn, pn);
        return;
    }

    // ---- merged MLP (V blocks then T blocks) ----
    short* As = smem;                            // [2][128*AP]
    short* Bs = smem + 2 * MBLK * AP;            // [2][256*AP]
    const bool isV = bid < VBLKS;
    const float* A    = isV ? Av : At;
    const short* B1t_ = isV ? B1v : B1t;
    const float* b1   = isV ? b1v : b1t;
    const short* B2t_ = isV ? B2v : B2t;
    const float* b2   = isV ? b2v : b2t;
    const int K = isV ? 2048 : 768;
    const int boff = isV ? 0 : 32;
    const int rowBase = (isV ? bid : bid - VBLKS) * MBLK;

    const int lane = tid & 63, wid = tid >> 6;
    const int wr = wid >> 2, wc = wid & 3;

    const int sar = tid >> 2, sac = (tid & 3) * 8;
    int aclamp = rowBase + sar; if (aclamp > NITEM - 1) aclamp = NITEM - 1;
    const float* aptr = A + (size_t)aclamp * K + sac;

    const int fk = (lane >> 4) * 8;
    const int faoff = (wr * 64 + (lane & 15)) * AP + fk;
    const int fboff = (wc * 64 + (lane & 15)) * AP + fk;

    floatx4 acc[4][4];
    #pragma unroll
    for (int m = 0; m < 4; m++)
        #pragma unroll
        for (int n = 0; n < 4; n++) acc[m][n] = (floatx4)0.f;

    float4 ra0, ra1;
    short8v rb0, rb1;
    const int nk = K >> 5;

    auto ldg = [&](int ks) {
        const float* ap = aptr + ks * 32;
        ra0 = *(const float4*)(ap);
        ra1 = *(const float4*)(ap + 4);
        const short* bsrc = B1t_ + (size_t)ks * 8192 + tid * 16;
        rb0 = *(const short8v*)(bsrc);
        rb1 = *(const short8v*)(bsrc + 8);
    };
    auto stv = [&](int buf) {
        uint4 av;
        av.x = cvt_pk_bf16(ra0.x, ra0.y); av.y = cvt_pk_bf16(ra0.z, ra0.w);
        av.z = cvt_pk_bf16(ra1.x, ra1.y); av.w = cvt_pk_bf16(ra1.z, ra1.w);
        *(uint4*)&As[buf * (MBLK * AP) + sar * AP + sac] = av;
        short* bd = &Bs[buf * (256 * AP) + (tid >> 1) * AP + (tid & 1) * 16];
        *(short8v*)(bd) = rb0;
        *(short8v*)(bd + 8) = rb1;
    };

    ldg(0); stv(0);
    __syncthreads();
    int cur = 0;
    for (int ks = 0; ks < nk; ++ks) {
        if (ks + 1 < nk) ldg(ks + 1);
        short8v a[4], b[4];
        #pragma unroll
        for (int m = 0; m < 4; m++) a[m] = *(const short8v*)&As[cur * (MBLK * AP) + faoff + m * 16 * AP];
        #pragma unroll
        for (int n = 0; n < 4; n++) b[n] = *(const short8v*)&Bs[cur * (256 * AP) + fboff + n * 16 * AP];
        #pragma unroll
        for (int m = 0; m < 4; m++)
            #pragma unroll
            for (int n = 0; n < 4; n++)
                acc[m][n] = __builtin_amdgcn_mfma_f32_16x16x32_bf16(a[m], b[n], acc[m][n], 0, 0, 0);
        if (ks + 1 < nk) stv(cur ^ 1);
        __syncthreads();
        cur ^= 1;
    }

    // phase 2: bias + lrelu -> bf16 mid in LDS (packed pair stores)
    unsigned* mid32 = (unsigned*)smem;           // [128][132]
    float bcol[4];
    #pragma unroll
    for (int n = 0; n < 4; n++) bcol[n] = b1[wc * 64 + n * 16 + (lane & 15)];
    #pragma unroll
    for (int m = 0; m < 4; m++)
        #pragma unroll
        for (int n = 0; n < 4; n++) {
            int col = wc * 64 + n * 16 + (lane & 15);
            #pragma unroll
            for (int q = 0; q < 4; q++) {
                int row = wr * 64 + m * 16 + (lane >> 4) * 4 + q;
                float v = acc[m][n][q] + bcol[n];
                v = v > 0.f ? v : 0.01f * v;
                float pn = __shfl_xor(v, 1, 64);
                if (!(lane & 1)) mid32[row * 132 + (col >> 1)] = cvt_pk_bf16(v, pn);
            }
        }
    __syncthreads();

    // phase 3: temp = mid @ W2
    const short* mid = smem;
    floatx4 acc2[4];
    #pragma unroll
    for (int n2 = 0; n2 < 4; n2++) acc2[n2] = (floatx4)0.f;
    const int arow = wid * 16 + (lane & 15);
    #pragma unroll
    for (int ks2 = 0; ks2 < 8; ++ks2) {
        short8v af = *(const short8v*)&mid[arow * MIDP + ks2 * 32 + fk];
        const short* bp = B2t_ + ks2 * 2048 + fk;
        short8v bf4[4];
        #pragma unroll
        for (int n2 = 0; n2 < 4; n2++) bf4[n2] = *(const short8v*)(bp + (n2 * 16 + (lane & 15)) * 32);
        #pragma unroll
        for (int n2 = 0; n2 < 4; n2++)
            acc2[n2] = __builtin_amdgcn_mfma_f32_16x16x32_bf16(af, bf4[n2], acc2[n2], 0, 0, 0);
    }

    // phase 4: bias + row-L2-norm, write packed bf16 x
    float b2c[4];
    #pragma unroll
    for (int n2 = 0; n2 < 4; n2++) b2c[n2] = b2[n2 * 16 + (lane & 15)];
    #pragma unroll
    for (int q = 0; q < 4; ++q) {
        float v[4]; float ss = 0.f;
        #pragma unroll
        for (int n2 = 0; n2 < 4; n2++) { v[n2] = acc2[n2][q] + b2c[n2]; ss += v[n2] * v[n2]; }
        ss += __shfl_xor(ss, 1, 64);
        ss += __shfl_xor(ss, 2, 64);
        ss += __shfl_xor(ss, 4, 64);
        ss += __shfl_xor(ss, 8, 64);
        float sc = 1.f / fmaxf(sqrtf(ss), 1e-12f);
        int lr = wid * 16 + (lane >> 4) * 4 + q;
        int grow = NUSER + rowBase + lr;
        bool ok = (rowBase + lr) < NITEM;
        #pragma unroll
        for (int n2 = 0; n2 < 4; n2++) {
            float xn = v[n2] * sc;
            float pn = __shfl_xor(xn, 1, 64);
            if (ok && !(lane & 1))
                xbf[(size_t)grow * 64 + boff + n2 * 8 + ((lane & 15) >> 1)] = cvt_pk_bf16(xn, pn);
        }
    }
}

// ---------------- hop 1: g1 = A_hat(x) (bf16), s = A_hat(1) ----------------
__global__ __launch_bounds__(256) void k_gather_p(const int* __restrict__ rowptr, const unsigned* __restrict__ csr_pkd,
                                                  const float* __restrict__ dinv, const unsigned* __restrict__ in_bf,
                                                  unsigned* __restrict__ out_bf, float* __restrict__ s_out) {
    int row = blockIdx.x * 4 + (threadIdx.x >> 6);
    int lane = threadIdx.x & 63;
    if (row >= NNODE) return;
    int p0 = rowptr[row], p1 = rowptr[row + 1];
    float dr = dinv[row];
    unsigned sv = in_bf[(size_t)row * 64 + lane];
    float ax0 = dr * bflo(sv), ay0 = dr * bfhi(sv);
    float ax1 = 0.f, ay1 = 0.f;
    float wsum = 0.f;
    for (int p = p0; p < p1; p += 64) {
        int c = p1 - p; if (c > 64) c = 64;
        unsigned pk = (lane < c) ? csr_pkd[p + lane] : 0u;
        wsum += bfhi(pk);
        int j = 0;
        for (; j + 4 <= c; j += 4) {
            unsigned e0 = __shfl(pk, j, 64),     e1 = __shfl(pk, j + 1, 64);
            unsigned e2 = __shfl(pk, j + 2, 64), e3 = __shfl(pk, j + 3, 64);
            unsigned v0 = in_bf[(size_t)(e0 & 0xffffu) * 64 + lane];
            unsigned v1 = in_bf[(size_t)(e1 & 0xffffu) * 64 + lane];
            unsigned v2 = in_bf[(size_t)(e2 & 0xffffu) * 64 + lane];
            unsigned v3 = in_bf[(size_t)(e3 & 0xffffu) * 64 + lane];
            float w0 = bfhi(e0), w1 = bfhi(e1), w2 = bfhi(e2), w3 = bfhi(e3);
            ax0 += w0 * bflo(v0); ay0 += w0 * bfhi(v0);
            ax1 += w1 * bflo(v1); ay1 += w1 * bfhi(v1);
            ax0 += w2 * bflo(v2); ay0 += w2 * bfhi(v2);
            ax1 += w3 * bflo(v3); ay1 += w3 * bfhi(v3);
        }
        for (; j < c; ++j) {
            unsigned e = __shfl(pk, j, 64);
            unsigned v = in_bf[(size_t)(e & 0xffffu) * 64 + lane];
            float w = bfhi(e);
            ax0 += w * bflo(v); ay0 += w * bfhi(v);
        }
    }
    out_bf[(size_t)row * 64 + lane] = cvt_pk_bf16(dr * (ax0 + ax1), dr * (ay0 + ay1));
    #pragma unroll
    for (int o = 32; o >= 1; o >>= 1) wsum += __shfl_xor(wsum, o, 64);
    if (lane == 0) s_out[row] = dr * (dr + wsum);
}

// ---------------- hop 2 fused with rep epilogue ----------------
__global__ __launch_bounds__(512) void k_gather2_rep(const int* __restrict__ rowptr, const unsigned* __restrict__ csr_pkd,
                                                     const float* __restrict__ dinv, const unsigned* __restrict__ g1,
                                                     const short* __restrict__ Bcat, const unsigned* __restrict__ x_bf,
                                                     const float* __restrict__ s, const float* __restrict__ bw,
                                                     const float* __restrict__ bb, const float* __restrict__ weight_u,
                                                     float* __restrict__ rep0, unsigned* __restrict__ rep_bf) {
    __shared__ short As[16 * 264];
    const int tid = threadIdx.x, lane = tid & 63, w = tid >> 6;   // 8 waves
    const int rowBase = blockIdx.x * 16;

    for (int rr = 0; rr < 2; ++rr) {
        int lrow = w * 2 + rr;
        int row = rowBase + lrow;
        int p0 = rowptr[row], p1 = rowptr[row + 1];
        float dr = dinv[row];
        unsigned sv = g1[(size_t)row * 64 + lane];
        float ax0 = dr * bflo(sv), ay0 = dr * bfhi(sv);
        float ax1 = 0.f, ay1 = 0.f;
        for (int p = p0; p < p1; p += 64) {
            int c = p1 - p; if (c > 64) c = 64;
            unsigned pk = (lane < c) ? csr_pkd[p + lane] : 0u;
            int j = 0;
            for (; j + 4 <= c; j += 4) {
                unsigned e0 = __shfl(pk, j, 64),     e1 = __shfl(pk, j + 1, 64);
                unsigned e2 = __shfl(pk, j + 2, 64), e3 = __shfl(pk, j + 3, 64);
                unsigned v0 = g1[(size_t)(e0 & 0xffffu) * 64 + lane];
                unsigned v1 = g1[(size_t)(e1 & 0xffffu) * 64 + lane];
                unsigned v2 = g1[(size_t)(e2 & 0xffffu) * 64 + lane];
                unsigned v3 = g1[(size_t)(e3 & 0xffffu) * 64 + lane];
                float w0 = bfhi(e0), w1 = bfhi(e1), w2 = bfhi(e2), w3 = bfhi(e3);
                ax0 += w0 * bflo(v0); ay0 += w0 * bfhi(v0);
                ax1 += w1 * bflo(v1); ay1 += w1 * bfhi(v1);
                ax0 += w2 * bflo(v2); ay0 += w2 * bfhi(v2);
                ax1 += w3 * bflo(v3); ay1 += w3 * bfhi(v3);
            }
            for (; j < c; ++j) {
                unsigned e = __shfl(pk, j, 64);
                unsigned v = g1[(size_t)(e & 0xffffu) * 64 + lane];
                float wj = bfhi(e);
                ax0 += wj * bflo(v); ay0 += wj * bfhi(v);
            }
        }
        *(unsigned*)&As[lrow * 264 + 2 * lane] = sv;
        *(unsigned*)&As[lrow * 264 + 128 + 2 * lane] = cvt_pk_bf16(dr * (ax0 + ax1), dr * (ay0 + ay1));
    }
    __syncthreads();

    const int fk = (lane >> 4) * 8;
    floatx4 acc = (floatx4)0.f;
    #pragma unroll
    for (int ks = 0; ks < 8; ++ks) {
        short8v af = *(const short8v*)&As[(lane & 15) * 264 + ks * 32 + fk];
        short8v bf = *(const short8v*)(Bcat + ks * 4096 + (w * 16 + (lane & 15)) * 32 + fk);
        acc = __builtin_amdgcn_mfma_f32_16x16x32_bf16(af, bf, acc, 0, 0, 0);
    }
    const int col = w * 16 + (lane & 15);
    const float bwc = bw[col], bbc = bb[col];
    #pragma unroll
    for (int q = 0; q < 4; ++q) {
        int lrow = (lane >> 4) * 4 + q;
        int row = rowBase + lrow;
        unsigned xw = x_bf[(size_t)row * 64 + (col >> 1)];
        float xval = (col & 1) ? bfhi(xw) : bflo(xw);
        float v = acc[q] + xval + s[row] * bwc + bbc;
        float wu = (row < NUSER) ? weight_u[row * 2 + (col >> 6)] : 1.0f;
        v *= wu;
        rep0[(size_t)row * 128 + col] = v;
        float pn = __shfl_xor(v, 1, 64);
        if (!(lane & 1))
            rep_bf[(size_t)row * 64 + (col >> 1)] = cvt_pk_bf16(v, pn);
    }
}

// fused: user aggregation + item-item layer 1
#define UBLK (NUSER * 64 / 256)   // 5000
__global__ __launch_bounds__(256) void k_user_item1(const float* __restrict__ rep0, const unsigned* __restrict__ rep_bf,
                                                    const int* __restrict__ ug, const float* __restrict__ uwm,
                                                    const int* __restrict__ mm_col, const float* __restrict__ mm_values,
                                                    float* __restrict__ out, unsigned* __restrict__ tmp_bf) {
    int bid = blockIdx.x;
    if (bid < UBLK) {
        int id = bid * 256 + threadIdx.x;
        int u = id >> 6, lane = id & 63;
        float2 acc = *(const float2*)(rep0 + (size_t)u * 128 + 2 * lane);   // self, f32-exact
        #pragma unroll 4
        for (int k = 0; k < KUSER; k++) {
            int nb = ug[u * KUSER + k];
            float w = uwm[u * KUSER + k];
            unsigned v = rep_bf[(size_t)nb * 64 + lane];
            acc.x += w * bflo(v);
            acc.y += w * bfhi(v);
        }
        *(float2*)(out + (size_t)u * 128 + 2 * lane) = acc;
    } else {
        int id = (bid - UBLK) * 256 + threadIdx.x;
        int r = id >> 6, lane = id & 63;
        float ax = 0.f, ay = 0.f;
        #pragma unroll
        for (int j = 0; j < KITEM; j++) {
            int c = mm_col[r * KITEM + j];
            float w = mm_values[r * KITEM + j];
            unsigned v = rep_bf[(size_t)(NUSER + c) * 64 + lane];
            ax += w * bflo(v);
            ay += w * bfhi(v);
        }
        tmp_bf[(size_t)r * 64 + lane] = cvt_pk_bf16(ax, ay);
    }
}

// item-item layer 2
__global__ __launch_bounds__(256) void k_item2(const float* __restrict__ rep0, const unsigned* __restrict__ tmp_bf,
                                               const int* __restrict__ mm_col, const float* __restrict__ mm_values,
                                               float* __restrict__ out) {
    int id = blockIdx.x * 256 + threadIdx.x;
    int r = id >> 6, lane = id & 63;
    if (r >= NITEM) return;
    float ax = 0.f, ay = 0.f;
    #pragma unroll
    for (int j = 0; j < KITEM; j++) {
        int c = mm_col[r * KITEM + j];
        float w = mm_values[r * KITEM + j];
        unsigned v = tmp_bf[(size_t)c * 64 + lane];
        ax += w * bflo(v);
        ay += w * bfhi(v);
    }
    float2 base = *(const float2*)(rep0 + (size_t)(NUSER + r) * 128 + 2 * lane);
    float2 o;
    o.x = base.x + ax;
    o.y = base.y + ay;
    *(float2*)(out + (size_t)(NUSER + r) * 128 + 2 * lane) = o;
}

extern "C" void kernel_launch(void* const* d_in, const int* in_sizes, int n_in,
                              void* d_out, int out_size, void* d_ws, size_t ws_size,
                              hipStream_t stream) {
    const int*   edge_index = (const int*)d_in[0];
    const float* v_feat   = (const float*)d_in[1];
    const float* t_feat   = (const float*)d_in[2];
    const float* v_pref   = (const float*)d_in[3];
    const float* t_pref   = (const float*)d_in[4];
    const float* v_mlp1_w = (const float*)d_in[5];
    const float* v_mlp1_b = (const float*)d_in[6];
    const float* v_mlp2_w = (const float*)d_in[7];
    const float* v_mlp2_b = (const float*)d_in[8];
    const float* t_mlp1_w = (const float*)d_in[9];
    const float* t_mlp1_b = (const float*)d_in[10];
    const float* t_mlp2_w = (const float*)d_in[11];
    const float* t_mlp2_b = (const float*)d_in[12];
    const float* v_conv_w = (const float*)d_in[13];
    const float* v_conv_b = (const float*)d_in[14];
    const float* t_conv_w = (const float*)d_in[15];
    const float* t_conv_b = (const float*)d_in[16];
    const float* weight_u = (const float*)d_in[17];
    const int*   user_graph = (const int*)d_in[18];
    const float* uwm      = (const float*)d_in[19];
    const int*   mm_indices = (const int*)d_in[20];
    const float* mm_values  = (const float*)d_in[21];
    float* out = (float*)d_out;

    char* wsb = (char*)d_ws;
    size_t off = 0;
    auto alloc = [&](size_t bytes) -> void* {
        void* p = wsb + off;
        off = (off + bytes + 255) & ~(size_t)255;
        return p;
    };
    int*      cnt     = (int*)     alloc(NNODE * 4);
    float*    dinv    = (float*)   alloc(NNODE * 4);
    int*      rowptr  = (int*)     alloc((NNODE + 1) * 4);
    int*      bsum    = (int*)     alloc(256 * 4);
    int*      cursor  = (int*)     alloc(NNODE * 4);
    unsigned* csr_pkd = (unsigned*)alloc((size_t)2 * NE * 4);
    short*    Btw_v   = (short*)   alloc((size_t)2048 * 256 * 2);
    short*    Btw_t   = (short*)   alloc((size_t)768 * 256 * 2);
    short*    W2b_v   = (short*)   alloc((size_t)256 * 64 * 2);
    short*    W2b_t   = (short*)   alloc((size_t)256 * 64 * 2);
    short*    Bcat    = (short*)   alloc((size_t)256 * 128 * 2);
    float*    bw      = (float*)   alloc(128 * 4);
    float*    bb      = (float*)   alloc(128 * 4);
    float*    svec    = (float*)   alloc(NNODE * 4);
    unsigned* x_bf    = (unsigned*)alloc((size_t)NNODE * 64 * 4);
    unsigned* g1      = (unsigned*)alloc((size_t)NNODE * 64 * 4);
    float*    rep0    = (float*)   alloc((size_t)NNODE * 128 * 4);
    unsigned* rep_bf  = (unsigned*)alloc((size_t)NNODE * 64 * 4);
    unsigned* tmp_bf  = (unsigned*)alloc((size_t)NITEM * 64 * 4);
    (void)ws_size; (void)n_in; (void)in_sizes; (void)out_size;

    const int* pairs_u  = edge_index;            // edge_index[0][0..NE)   = u
    const int* pairs_it = edge_index + NE;       // edge_index[0][NE..2NE) = it
    const int* mm_col = mm_indices + NITEM * KITEM;

    const int NB = (NNODE + 255) / 256;   // 235

    // mega A: degree count + weight transposes (independent, overlapped)
    hipMemsetAsync(cnt, 0, NNODE * 4, stream);
    k_count_transpose<<<CNTB + TRB, 256, 0, stream>>>(pairs_u, pairs_it, cnt,
                                                      v_mlp1_w, t_mlp1_w, v_mlp2_w, t_mlp2_w,
                                                      Btw_v, Btw_t, W2b_v, W2b_t);
    k_scanA<<<NB, 256, 0, stream>>>(cnt, rowptr, bsum, dinv, NNODE);
    k_scanB_prep<<<2, 256, 0, stream>>>(bsum, NB, v_conv_w, t_conv_w, v_conv_b, t_conv_b, Bcat, bw, bb);
    k_scanC<<<NB, 256, 0, stream>>>(rowptr, bsum, cursor, NNODE);

    // mega B: CSR fill + merged V+T MLP + pref L2-norm (independent, overlapped)
    k_fill_mlp_l2n<<<FILLB + MLPB + L2NB, 512, 0, stream>>>(
        pairs_u, pairs_it, dinv, cursor, csr_pkd,
        v_feat, t_feat, Btw_v, Btw_t, v_mlp1_b, t_mlp1_b,
        W2b_v, W2b_t, v_mlp2_b, t_mlp2_b, v_pref, t_pref, x_bf);

    // hop1 -> g1 + svec; hop2 fused with rep epilogue
    k_gather_p<<<(NNODE + 3) / 4, 256, 0, stream>>>(rowptr, csr_pkd, dinv, x_bf, g1, svec);
    k_gather2_rep<<<NNODE / 16, 512, 0, stream>>>(rowptr, csr_pkd, dinv, g1, Bcat, x_bf,
                                                  svec, bw, bb, weight_u, rep0, rep_bf);

    // users + item layer 1 (one grid), then item layer 2
    k_user_item1<<<UBLK + NITEM * 64 / 256, 256, 0, stream>>>(rep0, rep_bf, user_graph, uwm,
                                                              mm_col, mm_values, out, tmp_bf);
    k_item2<<<NITEM * 64 / 256, 256, 0, stream>>>(rep0, tmp_bf, mm_col, mm_values, out);
}